// Round 7
// baseline (8445.790 us; speedup 1.0000x reference)
//
#include <hip/hip_runtime.h>

#define NN 100000
#define NE 3200000

typedef unsigned int u32;

__device__ __forceinline__ int clampi(int s){
  s = s < 0 ? 0 : s;
  return s >= NN ? NN-1 : s;
}

template<int N4>
__device__ __forceinline__ float dotl(const float* __restrict__ a, const float* w){
  float acc = 0.f;
  #pragma unroll
  for (int k = 0; k < N4; ++k){
    float4 q = ((const float4*)w)[k];
    acc += a[4*k]*q.x + a[4*k+1]*q.y + a[4*k+2]*q.z + a[4*k+3]*q.w;
  }
  return acc;
}

// ---------------- khist: cnt[d]++ ------------------------------------------
__global__ __launch_bounds__(256,8) void khist(const int* __restrict__ ei, int* __restrict__ cnt){
  int i = blockIdx.x*256 + threadIdx.x;
  if (i >= NE) return;
  atomicAdd(&cnt[clampi(ei[NE+i])], 1);
}

// ---------------- kscan: off = exclusive_scan(cnt); cnt = 0 ----------------
__global__ void kscan(int* __restrict__ cnt, int* __restrict__ off){
  __shared__ int wsum[16];
  __shared__ int carry;
  int tid = threadIdx.x;
  if (tid == 0) carry = 0;
  __syncthreads();
  for (int base = 0; base < NN; base += 1024){
    int i = base + tid;
    int v = (i < NN) ? cnt[i] : 0;
    int x = v;
    #pragma unroll
    for (int ofs = 1; ofs < 64; ofs <<= 1){
      int t = __shfl_up(x, ofs, 64);
      if ((tid & 63) >= ofs) x += t;
    }
    if ((tid & 63) == 63) wsum[tid >> 6] = x;
    __syncthreads();
    if (tid < 16){
      int y = wsum[tid];
      #pragma unroll
      for (int ofs = 1; ofs < 16; ofs <<= 1){
        int t = __shfl_up(y, ofs, 64);
        if (tid >= ofs) y += t;
      }
      wsum[tid] = y;
    }
    __syncthreads();
    int wb = (tid >= 64) ? wsum[(tid >> 6) - 1] : 0;
    int incl = wb + x;
    if (i < NN){ off[i] = carry + incl - v; cnt[i] = 0; }
    int ctot = wsum[15];
    __syncthreads();
    if (tid == 0) carry += ctot;
    __syncthreads();
  }
  if (tid == 0) off[NN] = carry;
}

// ---------------- k1: h1 = x @ c1_Wx^T ; hs1 ; hd1 --------------------------
__global__ __launch_bounds__(256,4) void k1(const float* __restrict__ x,
    const float* __restrict__ Wx, const float* __restrict__ asrc, const float* __restrict__ adst,
    float* __restrict__ h1, float* __restrict__ hs1, float* __restrict__ hd1)
{
  __shared__ float wL[64], aS[16], aD[16];
  int tid = threadIdx.x;
  if (tid < 64) wL[tid] = Wx[tid];
  if (tid < 16){ aS[tid] = asrc[tid]; aD[tid] = adst[tid]; }
  __syncthreads();
  int n = blockIdx.x*256 + tid;
  if (n >= NN) return;
  float4 xr = ((const float4*)x)[n];
  float hs=0.f, hd=0.f;
  float* hrow = h1 + (size_t)n*16;
  #pragma unroll
  for (int j=0;j<16;j++){
    float h = xr.x*wL[j*4+0] + xr.y*wL[j*4+1] + xr.z*wL[j*4+2] + xr.w*wL[j*4+3];
    hrow[j] = h; hs += h*aS[j]; hd += h*aD[j];
  }
  hs1[n]=hs; hd1[n]=hd;
}

// ---------------- k2a: alpha1 -> scatter (ex, src) into CSR slot ------------
__global__ __launch_bounds__(256,8) void k2a(const int* __restrict__ ei,
    const float* __restrict__ ea, const float* __restrict__ We, const float* __restrict__ aedge,
    const float* __restrict__ hs1, const float* __restrict__ hd1,
    const int* __restrict__ off, int* __restrict__ cnt, float2* __restrict__ edata)
{
  __shared__ float w6[6];
  int tid = threadIdx.x;
  if (tid < 6){
    float acc = 0.f;
    for (int j=0;j<16;j++) acc += aedge[j] * We[j*6+tid];
    w6[tid] = acc;
  }
  __syncthreads();
  int i = blockIdx.x*256 + tid;
  if (i >= NE) return;
  int s = clampi(ei[i]);
  int d = clampi(ei[NE + i]);
  const float2* eap = (const float2*)ea + (size_t)i*3;
  float2 u0 = eap[0], u1 = eap[1], u2 = eap[2];
  float al = hs1[s] + hd1[d]
    + u0.x*w6[0] + u0.y*w6[1] + u1.x*w6[2]
    + u1.y*w6[3] + u2.x*w6[4] + u2.y*w6[5];
  al = al > 0.f ? al : 0.2f*al;
  float ex = __expf(al);
  int pos = off[d] + atomicAdd(&cnt[d], 1);
  edata[pos] = make_float2(ex, __int_as_float(s));
}

// ---------------- kagg: per-node CSR reduce (16 lanes = 16 features) --------
__global__ __launch_bounds__(256,4) void kagg(const float2* __restrict__ edata,
    const int* __restrict__ off, const float* __restrict__ h,
    float* __restrict__ acc, float* __restrict__ s, int* __restrict__ cnt)
{
  int n = (blockIdx.x*256 + threadIdx.x) >> 4;
  int j = threadIdx.x & 15;
  if (n >= NN) return;
  int beg = off[n], end = off[n+1];
  float aj = 0.f, sl = 0.f;
  for (int k = beg; k < end; ++k){
    float2 p = edata[k];
    int src = __float_as_int(p.y);
    aj += p.x * h[(size_t)src*16 + j];
    sl += p.x;
  }
  acc[(size_t)n*16 + j] = aj;
  if (j == 0){ s[n] = sl; cnt[n] = 0; }
}

// ---------------- k4: x1 = acc/s + b1 ; h2 = x1 @ c2_Wx^T ; hs2 ; hd2 -------
__global__ __launch_bounds__(256,4) void k4(const float* __restrict__ accb,
    const float* __restrict__ sb, const float* __restrict__ c1b, const float* __restrict__ Wx2,
    const float* __restrict__ a2s, const float* __restrict__ a2d,
    float* __restrict__ x1, float* __restrict__ h2,
    float* __restrict__ hs2, float* __restrict__ hd2)
{
  __shared__ float wL[256], bL[16], aS[16], aD[16];
  int tid = threadIdx.x;
  wL[tid] = Wx2[tid];
  if (tid < 16){ bL[tid]=c1b[tid]; aS[tid]=a2s[tid]; aD[tid]=a2d[tid]; }
  __syncthreads();
  int n = blockIdx.x*256 + tid;
  if (n >= NN) return;
  float inv = 1.f/(sb[n] + 1e-16f);
  float v[16];
  const float* xp = accb + (size_t)n*16;
  float* x1r = x1 + (size_t)n*16;
  #pragma unroll
  for (int j=0;j<16;j++){ v[j] = xp[j]*inv + bL[j]; x1r[j] = v[j]; }
  float hs=0.f, hd=0.f;
  float* h2r = h2 + (size_t)n*16;
  #pragma unroll
  for (int j=0;j<16;j++){
    float acc = 0.f;
    #pragma unroll
    for (int k=0;k<16;k++) acc += v[k]*wL[j*16+k];
    h2r[j] = acc; hs += acc*aS[j]; hd += acc*aD[j];
  }
  hs2[n]=hs; hd2[n]=hd;
}

// ---------------- k5: edge MLP + edge head + alpha2 scatter -----------------
// (256,4): VGPR budget 128. Round6 showed the w1-split body fits in 88 VGPRs;
// layers 2/3 are fused in two K-halves to keep peak live set ~100 floats so
// the tighter budget cannot re-introduce scratch spill (round5: 1.49GB spill).
__global__ __launch_bounds__(256,4) void k5(
    const int* __restrict__ ei, const float* __restrict__ ea,
    const float* __restrict__ x1,
    const float* __restrict__ hs2, const float* __restrict__ hd2,
    const float* w1p, const float* b1p, const float* w2p, const float* b2p,
    const float* w3p, const float* b3p, const float* w4p, const float* b4p,
    const float* We2, const float* a2e,
    const float* ew1p, const float* eb1p, const float* ew2p, const float* eb2p,
    const int* __restrict__ off, int* __restrict__ cnt, float2* __restrict__ edata,
    float* __restrict__ eout)
{
  __shared__ __align__(16) float w1sL[32*16];
  __shared__ __align__(16) float w1eL[32*8];
  __shared__ __align__(16) float w1dL[32*16];
  __shared__ float b1L[32];
  __shared__ __align__(16) float w2L[64*32]; __shared__ float b2L[64];
  __shared__ __align__(16) float w3L[32*64]; __shared__ float b3L[32];
  __shared__ __align__(16) float w4L[16*32]; __shared__ float b4L[16];
  __shared__ __align__(16) float ew1L[16*16]; __shared__ float eb1L[16];
  __shared__ __align__(16) float ew2L[4*16];  __shared__ float eb2L[4];
  __shared__ float w16L[16];
  int tid = threadIdx.x;
  for (int idx=tid; idx<512; idx+=256){
    int j=idx>>4, k=idx&15;
    w1sL[idx] = w1p[j*38+k];
    w1dL[idx] = w1p[j*38+22+k];
  }
  if (tid < 256){ int j=tid>>3, k=tid&7; w1eL[tid] = (k<6) ? w1p[j*38+16+k] : 0.f; }
  for (int idx=tid; idx<64*32; idx+=256) w2L[idx] = w2p[idx];
  for (int idx=tid; idx<32*64; idx+=256) w3L[idx] = w3p[idx];
  for (int idx=tid; idx<16*32; idx+=256) w4L[idx] = w4p[idx];
  ew1L[tid] = ew1p[tid];
  if (tid < 64){ ew2L[tid] = ew2p[tid]; b2L[tid] = b2p[tid]; }
  if (tid < 32){ b1L[tid] = b1p[tid]; b3L[tid] = b3p[tid]; }
  if (tid < 16){
    b4L[tid]=b4p[tid]; eb1L[tid]=eb1p[tid];
    float acc=0.f;
    for (int j=0;j<16;j++) acc += a2e[j] * We2[j*16+tid];
    w16L[tid]=acc;
  }
  if (tid < 4) eb2L[tid] = eb2p[tid];
  __syncthreads();

  int i = blockIdx.x*256 + tid;
  if (i >= NE) return;
  int s = clampi(ei[i]);
  int d = clampi(ei[NE + i]);

  float a1[32];
  {
    float xs[16], xd[16], ea8[8];
    const float4* xsp = (const float4*)(x1 + (size_t)s*16);
    const float4* xdp = (const float4*)(x1 + (size_t)d*16);
    #pragma unroll
    for (int q=0;q<4;q++){
      float4 a = xsp[q]; xs[4*q]=a.x; xs[4*q+1]=a.y; xs[4*q+2]=a.z; xs[4*q+3]=a.w;
      float4 b = xdp[q]; xd[4*q]=b.x; xd[4*q+1]=b.y; xd[4*q+2]=b.z; xd[4*q+3]=b.w;
    }
    const float2* eap = (const float2*)ea + (size_t)i*3;
    float2 u0=eap[0], u1=eap[1], u2=eap[2];
    ea8[0]=u0.x; ea8[1]=u0.y; ea8[2]=u1.x; ea8[3]=u1.y; ea8[4]=u2.x; ea8[5]=u2.y;
    ea8[6]=0.f; ea8[7]=0.f;
    #pragma unroll
    for (int j=0;j<32;j++){
      float v = dotl<4>(xs, &w1sL[j*16]) + dotl<2>(ea8, &w1eL[j*8])
              + dotl<4>(xd, &w1dL[j*16]) + b1L[j];
      a1[j] = fmaxf(v, 0.f);
    }
  }
  // layers 2+3 fused in two K-halves: peak live = a1[32]+t32[32]+a3acc[32]
  float a3acc[32];
  #pragma unroll
  for (int j=0;j<32;j++) a3acc[j] = b3L[j];
  #pragma unroll
  for (int h2i=0; h2i<2; ++h2i){
    float t32[32];
    #pragma unroll
    for (int j=0;j<32;j++) t32[j] = fmaxf(dotl<8>(a1, &w2L[(h2i*32+j)*32]) + b2L[h2i*32+j], 0.f);
    #pragma unroll
    for (int j=0;j<32;j++) a3acc[j] += dotl<8>(t32, &w3L[j*64 + h2i*32]);
  }
  float a3[32];
  #pragma unroll
  for (int j=0;j<32;j++) a3[j] = fmaxf(a3acc[j], 0.f);
  float e[16];
  #pragma unroll
  for (int j=0;j<16;j++) e[j] = dotl<8>(a3, &w4L[j*32]) + b4L[j];

  // edge head + log_softmax(4)
  float t[16];
  #pragma unroll
  for (int j=0;j<16;j++) t[j] = fmaxf(dotl<4>(e, &ew1L[j*16]) + eb1L[j], 0.f);
  float y0 = fmaxf(dotl<4>(t, &ew2L[0])  + eb2L[0], 0.f);
  float y1 = fmaxf(dotl<4>(t, &ew2L[16]) + eb2L[1], 0.f);
  float y2 = fmaxf(dotl<4>(t, &ew2L[32]) + eb2L[2], 0.f);
  float y3 = fmaxf(dotl<4>(t, &ew2L[48]) + eb2L[3], 0.f);
  float m = fmaxf(fmaxf(y0,y1), fmaxf(y2,y3));
  float l = m + __logf(__expf(y0-m)+__expf(y1-m)+__expf(y2-m)+__expf(y3-m));
  float4 eo; eo.x = y0-l; eo.y = y1-l; eo.z = y2-l; eo.w = y3-l;
  ((float4*)eout)[i] = eo;

  // conv2 alpha -> CSR scatter
  float al = hs2[s] + hd2[d];
  #pragma unroll
  for (int k=0;k<16;k++) al += e[k]*w16L[k];
  al = al > 0.f ? al : 0.2f*al;
  float ex = __expf(al);
  int pos = off[d] + atomicAdd(&cnt[d], 1);
  edata[pos] = make_float2(ex, __int_as_float(s));
}

// ---------------- k7: x2 -> node head -> log_softmax(2) --------------------
__global__ __launch_bounds__(256,4) void k7(const float* __restrict__ accb,
    const float* __restrict__ sb, const float* __restrict__ c2b,
    const float* __restrict__ w1p, const float* __restrict__ b1p,
    const float* __restrict__ w2p, const float* __restrict__ b2p,
    float* __restrict__ nout)
{
  __shared__ float wL[256], bL[16], w2L[32], b2L[2], cb[16];
  int tid = threadIdx.x;
  wL[tid] = w1p[tid];
  if (tid < 16){ bL[tid]=b1p[tid]; cb[tid]=c2b[tid]; }
  if (tid < 32) w2L[tid] = w2p[tid];
  if (tid < 2)  b2L[tid] = b2p[tid];
  __syncthreads();
  int n = blockIdx.x*256 + tid;
  if (n >= NN) return;
  float inv = 1.f/(sb[n] + 1e-16f);
  const float* xp = accb + (size_t)n*16;
  float v[16];
  #pragma unroll
  for (int j=0;j<16;j++) v[j] = xp[j]*inv + cb[j];
  float t[16];
  #pragma unroll
  for (int j=0;j<16;j++){
    float acc = bL[j];
    #pragma unroll
    for (int k=0;k<16;k++) acc += v[k]*wL[j*16+k];
    t[j] = fmaxf(acc, 0.f);
  }
  float y0 = b2L[0], y1 = b2L[1];
  #pragma unroll
  for (int k=0;k<16;k++){ y0 += t[k]*w2L[k]; y1 += t[k]*w2L[16+k]; }
  y0 = fmaxf(y0, 0.f); y1 = fmaxf(y1, 0.f);
  float m = fmaxf(y0, y1);
  float l = m + __logf(__expf(y0-m) + __expf(y1-m));
  float2 no; no.x = y0-l; no.y = y1-l;
  ((float2*)nout)[n] = no;
}

extern "C" void kernel_launch(void* const* d_in, const int* in_sizes, int n_in,
                              void* d_out, int out_size, void* d_ws, size_t ws_size,
                              hipStream_t stream)
{
  const float* x  = (const float*)d_in[0];
  const int* ei   = (const int*)d_in[1];
  const float* ea = (const float*)d_in[2];
  const float* c1Wx = (const float*)d_in[3];
  const float* c1We = (const float*)d_in[4];
  const float* c1as = (const float*)d_in[5];
  const float* c1ad = (const float*)d_in[6];
  const float* c1ae = (const float*)d_in[7];
  const float* c1b  = (const float*)d_in[8];
  const float* e1w1 = (const float*)d_in[9];
  const float* e1b1 = (const float*)d_in[10];
  const float* e1w2 = (const float*)d_in[11];
  const float* e1b2 = (const float*)d_in[12];
  const float* e1w3 = (const float*)d_in[13];
  const float* e1b3 = (const float*)d_in[14];
  const float* e1w4 = (const float*)d_in[15];
  const float* e1b4 = (const float*)d_in[16];
  const float* c2Wx = (const float*)d_in[17];
  const float* c2We = (const float*)d_in[18];
  const float* c2as = (const float*)d_in[19];
  const float* c2ad = (const float*)d_in[20];
  const float* c2ae = (const float*)d_in[21];
  const float* c2b  = (const float*)d_in[22];
  const float* nlw1 = (const float*)d_in[23];
  const float* nlb1 = (const float*)d_in[24];
  const float* nlw2 = (const float*)d_in[25];
  const float* nlb2 = (const float*)d_in[26];
  const float* elw1 = (const float*)d_in[27];
  const float* elb1 = (const float*)d_in[28];
  const float* elw2 = (const float*)d_in[29];
  const float* elb2 = (const float*)d_in[30];

  float* ws = (float*)d_ws;
  const size_t N = NN;
  int* off   = (int*)ws;                 // N+1
  int* cnt   = (int*)ws + (N + 4);       // N
  float* h   = ws + 2*N + 8;             // 16N (h1, then h2)
  float* hs  = h  + 16*N;                // N  (hs1, then hs2)
  float* hd  = hs + N;                   // N
  float* x1  = hd + N;                   // 16N
  float* acc = x1 + 16*N;                // 16N
  float* s   = acc + 16*N;               // N
  float2* edata = (float2*)(s + N);      // NE float2

  float* nout = (float*)d_out;            // [100000, 2]
  float* eout = (float*)d_out + 200000;   // [3200000, 4]

  const int GE = (NE + 255)/256;
  const int GN = (NN + 255)/256;

  hipMemsetAsync(cnt, 0, N*sizeof(int), stream);
  khist<<<GE, 256, 0, stream>>>(ei, cnt);
  kscan<<<1, 1024, 0, stream>>>(cnt, off);          // off = scan(cnt); cnt = 0
  k1<<<GN, 256, 0, stream>>>(x, c1Wx, c1as, c1ad, h, hs, hd);
  k2a<<<GE, 256, 0, stream>>>(ei, ea, c1We, c1ae, hs, hd, off, cnt, edata);
  kagg<<<(NN+15)/16, 256, 0, stream>>>(edata, off, h, acc, s, cnt);   // also re-zeros cnt
  k4<<<GN, 256, 0, stream>>>(acc, s, c1b, c2Wx, c2as, c2ad, x1, h, hs, hd);
  k5<<<GE, 256, 0, stream>>>(ei, ea, x1, hs, hd,
      e1w1, e1b1, e1w2, e1b2, e1w3, e1b3, e1w4, e1b4,
      c2We, c2ae, elw1, elb1, elw2, elb2,
      off, cnt, edata, eout);
  kagg<<<(NN+15)/16, 256, 0, stream>>>(edata, off, h, acc, s, cnt);
  k7<<<GN, 256, 0, stream>>>(acc, s, c2b, nlw1, nlb1, nlw2, nlb2, nout);
}

// Round 8
// 1380.903 us; speedup vs baseline: 6.1161x; 6.1161x over previous
//
#include <hip/hip_runtime.h>

#define NN 100000
#define NE 3200000

typedef unsigned int u32;

__device__ __forceinline__ int clampi(int s){
  s = s < 0 ? 0 : s;
  return s >= NN ? NN-1 : s;
}

// dual-accumulator dot: halves the dependent-FMA chain
template<int N4>
__device__ __forceinline__ float dotl(const float* __restrict__ a, const float* w){
  float acc0 = 0.f, acc1 = 0.f;
  #pragma unroll
  for (int k = 0; k < N4; k += 2){
    float4 q0 = ((const float4*)w)[k];
    acc0 += a[4*k]*q0.x + a[4*k+1]*q0.y + a[4*k+2]*q0.z + a[4*k+3]*q0.w;
    float4 q1 = ((const float4*)w)[k+1];
    acc1 += a[4*k+4]*q1.x + a[4*k+5]*q1.y + a[4*k+6]*q1.z + a[4*k+7]*q1.w;
  }
  return acc0 + acc1;
}

// ---------------- khist: cnt[d]++ ------------------------------------------
__global__ __launch_bounds__(256,8) void khist(const int* __restrict__ ei, int* __restrict__ cnt){
  int i = blockIdx.x*256 + threadIdx.x;
  if (i >= NE) return;
  atomicAdd(&cnt[clampi(ei[NE+i])], 1);
}

// ---------------- kscan: off = exclusive_scan(cnt); cnt = 0 ----------------
__global__ void kscan(int* __restrict__ cnt, int* __restrict__ off){
  __shared__ int wsum[16];
  __shared__ int carry;
  int tid = threadIdx.x;
  if (tid == 0) carry = 0;
  __syncthreads();
  for (int base = 0; base < NN; base += 1024){
    int i = base + tid;
    int v = (i < NN) ? cnt[i] : 0;
    int x = v;
    #pragma unroll
    for (int ofs = 1; ofs < 64; ofs <<= 1){
      int t = __shfl_up(x, ofs, 64);
      if ((tid & 63) >= ofs) x += t;
    }
    if ((tid & 63) == 63) wsum[tid >> 6] = x;
    __syncthreads();
    if (tid < 16){
      int y = wsum[tid];
      #pragma unroll
      for (int ofs = 1; ofs < 16; ofs <<= 1){
        int t = __shfl_up(y, ofs, 64);
        if (tid >= ofs) y += t;
      }
      wsum[tid] = y;
    }
    __syncthreads();
    int wb = (tid >= 64) ? wsum[(tid >> 6) - 1] : 0;
    int incl = wb + x;
    if (i < NN){ off[i] = carry + incl - v; cnt[i] = 0; }
    int ctot = wsum[15];
    __syncthreads();
    if (tid == 0) carry += ctot;
    __syncthreads();
  }
  if (tid == 0) off[NN] = carry;
}

// ---------------- k1: h1 = x @ c1_Wx^T ; hs1 ; hd1 --------------------------
__global__ __launch_bounds__(256,4) void k1(const float* __restrict__ x,
    const float* __restrict__ Wx, const float* __restrict__ asrc, const float* __restrict__ adst,
    float* __restrict__ h1, float* __restrict__ hs1, float* __restrict__ hd1)
{
  __shared__ float wL[64], aS[16], aD[16];
  int tid = threadIdx.x;
  if (tid < 64) wL[tid] = Wx[tid];
  if (tid < 16){ aS[tid] = asrc[tid]; aD[tid] = adst[tid]; }
  __syncthreads();
  int n = blockIdx.x*256 + tid;
  if (n >= NN) return;
  float4 xr = ((const float4*)x)[n];
  float hs=0.f, hd=0.f;
  float* hrow = h1 + (size_t)n*16;
  #pragma unroll
  for (int j=0;j<16;j++){
    float h = xr.x*wL[j*4+0] + xr.y*wL[j*4+1] + xr.z*wL[j*4+2] + xr.w*wL[j*4+3];
    hrow[j] = h; hs += h*aS[j]; hd += h*aD[j];
  }
  hs1[n]=hs; hd1[n]=hd;
}

// ---------------- k2a: alpha1 -> scatter (ex, src) into CSR slot ------------
__global__ __launch_bounds__(256,8) void k2a(const int* __restrict__ ei,
    const float* __restrict__ ea, const float* __restrict__ We, const float* __restrict__ aedge,
    const float* __restrict__ hs1, const float* __restrict__ hd1,
    const int* __restrict__ off, int* __restrict__ cnt, float2* __restrict__ edata)
{
  __shared__ float w6[6];
  int tid = threadIdx.x;
  if (tid < 6){
    float acc = 0.f;
    for (int j=0;j<16;j++) acc += aedge[j] * We[j*6+tid];
    w6[tid] = acc;
  }
  __syncthreads();
  int i = blockIdx.x*256 + tid;
  if (i >= NE) return;
  int s = clampi(ei[i]);
  int d = clampi(ei[NE + i]);
  const float2* eap = (const float2*)ea + (size_t)i*3;
  float2 u0 = eap[0], u1 = eap[1], u2 = eap[2];
  float al = hs1[s] + hd1[d]
    + u0.x*w6[0] + u0.y*w6[1] + u1.x*w6[2]
    + u1.y*w6[3] + u2.x*w6[4] + u2.y*w6[5];
  al = al > 0.f ? al : 0.2f*al;
  float ex = __expf(al);
  int pos = off[d] + atomicAdd(&cnt[d], 1);
  edata[pos] = make_float2(ex, __int_as_float(s));
}

// ---------------- kagg: per-node CSR reduce (16 lanes = 16 features) --------
__global__ __launch_bounds__(256,4) void kagg(const float2* __restrict__ edata,
    const int* __restrict__ off, const float* __restrict__ h,
    float* __restrict__ acc, float* __restrict__ s, int* __restrict__ cnt)
{
  int n = (blockIdx.x*256 + threadIdx.x) >> 4;
  int j = threadIdx.x & 15;
  if (n >= NN) return;
  int beg = off[n], end = off[n+1];
  float aj = 0.f, sl = 0.f;
  for (int k = beg; k < end; ++k){
    float2 p = edata[k];
    int src = __float_as_int(p.y);
    aj += p.x * h[(size_t)src*16 + j];
    sl += p.x;
  }
  acc[(size_t)n*16 + j] = aj;
  if (j == 0){ s[n] = sl; cnt[n] = 0; }
}

// ---------------- k4: x1 = acc/s + b1 ; h2 ; hs2 ; hd2 ; u = W1s.x1 ; v = W1d.x1
__global__ __launch_bounds__(256,2) void k4(const float* __restrict__ accb,
    const float* __restrict__ sb, const float* __restrict__ c1b, const float* __restrict__ Wx2,
    const float* __restrict__ a2s, const float* __restrict__ a2d,
    const float* __restrict__ w1p,
    float* __restrict__ x1, float* __restrict__ h2,
    float* __restrict__ hs2, float* __restrict__ hd2,
    float* __restrict__ u, float* __restrict__ v)
{
  __shared__ float wL[256], bL[16], aS[16], aD[16];
  __shared__ float w1sL[32*16], w1dL[32*16];
  int tid = threadIdx.x;
  wL[tid] = Wx2[tid];
  if (tid < 16){ bL[tid]=c1b[tid]; aS[tid]=a2s[tid]; aD[tid]=a2d[tid]; }
  for (int idx=tid; idx<512; idx+=256){
    int j=idx>>4, k=idx&15;
    w1sL[idx] = w1p[j*38+k];
    w1dL[idx] = w1p[j*38+22+k];
  }
  __syncthreads();
  int n = blockIdx.x*256 + tid;
  if (n >= NN) return;
  float inv = 1.f/(sb[n] + 1e-16f);
  float xv[16];
  const float* xp = accb + (size_t)n*16;
  float* x1r = x1 + (size_t)n*16;
  #pragma unroll
  for (int j=0;j<16;j++){ xv[j] = xp[j]*inv + bL[j]; x1r[j] = xv[j]; }
  float hs=0.f, hd=0.f;
  float* h2r = h2 + (size_t)n*16;
  #pragma unroll
  for (int j=0;j<16;j++){
    float acc = 0.f;
    #pragma unroll
    for (int k=0;k<16;k++) acc += xv[k]*wL[j*16+k];
    h2r[j] = acc; hs += acc*aS[j]; hd += acc*aD[j];
  }
  hs2[n]=hs; hd2[n]=hd;
  float* ur = u + (size_t)n*32;
  float* vr = v + (size_t)n*32;
  #pragma unroll
  for (int j=0;j<32;j++){
    ur[j] = dotl<4>(xv, &w1sL[j*16]);
    vr[j] = dotl<4>(xv, &w1dL[j*16]);
  }
}

// ---------------- k5: edge MLP + edge head + alpha2 scatter -----------------
// r6 body (known: VGPR=88, no spill) with layer1 factored through u[s]/v[d].
// (256,3): VGPR budget ~170 >> ~110 live set -> spill-safe.
__global__ __launch_bounds__(256,3) void k5(
    const int* __restrict__ ei, const float* __restrict__ ea,
    const float* __restrict__ u, const float* __restrict__ v,
    const float* __restrict__ hs2, const float* __restrict__ hd2,
    const float* w1p, const float* b1p, const float* w2p, const float* b2p,
    const float* w3p, const float* b3p, const float* w4p, const float* b4p,
    const float* We2, const float* a2e,
    const float* ew1p, const float* eb1p, const float* ew2p, const float* eb2p,
    const int* __restrict__ off, int* __restrict__ cnt, float2* __restrict__ edata,
    float* __restrict__ eout)
{
  __shared__ __align__(16) float w1eL[32*8];
  __shared__ float b1L[32];
  __shared__ __align__(16) float w2L[64*32]; __shared__ float b2L[64];
  __shared__ __align__(16) float w3L[32*64]; __shared__ float b3L[32];
  __shared__ __align__(16) float w4L[16*32]; __shared__ float b4L[16];
  __shared__ __align__(16) float ew1L[16*16]; __shared__ float eb1L[16];
  __shared__ __align__(16) float ew2L[4*16];  __shared__ float eb2L[4];
  __shared__ float w16L[16];
  int tid = threadIdx.x;
  if (tid < 256){ int j=tid>>3, k=tid&7; w1eL[tid] = (k<6) ? w1p[j*38+16+k] : 0.f; }
  for (int idx=tid; idx<64*32; idx+=256) w2L[idx] = w2p[idx];
  for (int idx=tid; idx<32*64; idx+=256) w3L[idx] = w3p[idx];
  for (int idx=tid; idx<16*32; idx+=256) w4L[idx] = w4p[idx];
  ew1L[tid] = ew1p[tid];
  if (tid < 64){ ew2L[tid] = ew2p[tid]; b2L[tid] = b2p[tid]; }
  if (tid < 32){ b1L[tid] = b1p[tid]; b3L[tid] = b3p[tid]; }
  if (tid < 16){
    b4L[tid]=b4p[tid]; eb1L[tid]=eb1p[tid];
    float acc=0.f;
    for (int j=0;j<16;j++) acc += a2e[j] * We2[j*16+tid];
    w16L[tid]=acc;
  }
  if (tid < 4) eb2L[tid] = eb2p[tid];
  __syncthreads();

  int i = blockIdx.x*256 + tid;
  if (i >= NE) return;
  int s = clampi(ei[i]);
  int d = clampi(ei[NE + i]);

  float a1[32];
  {
    float ea8[8];
    const float2* eap = (const float2*)ea + (size_t)i*3;
    float2 u0=eap[0], u1=eap[1], u2=eap[2];
    ea8[0]=u0.x; ea8[1]=u0.y; ea8[2]=u1.x; ea8[3]=u1.y; ea8[4]=u2.x; ea8[5]=u2.y;
    ea8[6]=0.f; ea8[7]=0.f;
    const float4* up = (const float4*)(u + (size_t)s*32);
    const float4* vp = (const float4*)(v + (size_t)d*32);
    #pragma unroll
    for (int q=0;q<8;q++){
      float4 uq = up[q];
      float4 vq = vp[q];
      a1[4*q+0] = fmaxf(uq.x + vq.x + dotl<2>(ea8, &w1eL[(4*q+0)*8]) + b1L[4*q+0], 0.f);
      a1[4*q+1] = fmaxf(uq.y + vq.y + dotl<2>(ea8, &w1eL[(4*q+1)*8]) + b1L[4*q+1], 0.f);
      a1[4*q+2] = fmaxf(uq.z + vq.z + dotl<2>(ea8, &w1eL[(4*q+2)*8]) + b1L[4*q+2], 0.f);
      a1[4*q+3] = fmaxf(uq.w + vq.w + dotl<2>(ea8, &w1eL[(4*q+3)*8]) + b1L[4*q+3], 0.f);
    }
  }
  float a2[64];
  #pragma unroll
  for (int j=0;j<64;j++) a2[j] = fmaxf(dotl<8>(a1, &w2L[j*32]) + b2L[j], 0.f);
  float a3[32];
  #pragma unroll
  for (int j=0;j<32;j++) a3[j] = fmaxf(dotl<16>(a2, &w3L[j*64]) + b3L[j], 0.f);
  float e[16];
  #pragma unroll
  for (int j=0;j<16;j++) e[j] = dotl<8>(a3, &w4L[j*32]) + b4L[j];

  // edge head + log_softmax(4)
  float t[16];
  #pragma unroll
  for (int j=0;j<16;j++) t[j] = fmaxf(dotl<4>(e, &ew1L[j*16]) + eb1L[j], 0.f);
  float y0 = fmaxf(dotl<4>(t, &ew2L[0])  + eb2L[0], 0.f);
  float y1 = fmaxf(dotl<4>(t, &ew2L[16]) + eb2L[1], 0.f);
  float y2 = fmaxf(dotl<4>(t, &ew2L[32]) + eb2L[2], 0.f);
  float y3 = fmaxf(dotl<4>(t, &ew2L[48]) + eb2L[3], 0.f);
  float m = fmaxf(fmaxf(y0,y1), fmaxf(y2,y3));
  float l = m + __logf(__expf(y0-m)+__expf(y1-m)+__expf(y2-m)+__expf(y3-m));
  float4 eo; eo.x = y0-l; eo.y = y1-l; eo.z = y2-l; eo.w = y3-l;
  ((float4*)eout)[i] = eo;

  // conv2 alpha -> CSR scatter
  float al = hs2[s] + hd2[d];
  #pragma unroll
  for (int k=0;k<16;k++) al += e[k]*w16L[k];
  al = al > 0.f ? al : 0.2f*al;
  float ex = __expf(al);
  int pos = off[d] + atomicAdd(&cnt[d], 1);
  edata[pos] = make_float2(ex, __int_as_float(s));
}

// ---------------- k7: x2 -> node head -> log_softmax(2) --------------------
__global__ __launch_bounds__(256,4) void k7(const float* __restrict__ accb,
    const float* __restrict__ sb, const float* __restrict__ c2b,
    const float* __restrict__ w1p, const float* __restrict__ b1p,
    const float* __restrict__ w2p, const float* __restrict__ b2p,
    float* __restrict__ nout)
{
  __shared__ float wL[256], bL[16], w2L[32], b2L[2], cb[16];
  int tid = threadIdx.x;
  wL[tid] = w1p[tid];
  if (tid < 16){ bL[tid]=b1p[tid]; cb[tid]=c2b[tid]; }
  if (tid < 32) w2L[tid] = w2p[tid];
  if (tid < 2)  b2L[tid] = b2p[tid];
  __syncthreads();
  int n = blockIdx.x*256 + tid;
  if (n >= NN) return;
  float inv = 1.f/(sb[n] + 1e-16f);
  const float* xp = accb + (size_t)n*16;
  float v[16];
  #pragma unroll
  for (int j=0;j<16;j++) v[j] = xp[j]*inv + cb[j];
  float t[16];
  #pragma unroll
  for (int j=0;j<16;j++){
    float acc = bL[j];
    #pragma unroll
    for (int k=0;k<16;k++) acc += v[k]*wL[j*16+k];
    t[j] = fmaxf(acc, 0.f);
  }
  float y0 = b2L[0], y1 = b2L[1];
  #pragma unroll
  for (int k=0;k<16;k++){ y0 += t[k]*w2L[k]; y1 += t[k]*w2L[16+k]; }
  y0 = fmaxf(y0, 0.f); y1 = fmaxf(y1, 0.f);
  float m = fmaxf(y0, y1);
  float l = m + __logf(__expf(y0-m) + __expf(y1-m));
  float2 no; no.x = y0-l; no.y = y1-l;
  ((float2*)nout)[n] = no;
}

extern "C" void kernel_launch(void* const* d_in, const int* in_sizes, int n_in,
                              void* d_out, int out_size, void* d_ws, size_t ws_size,
                              hipStream_t stream)
{
  const float* x  = (const float*)d_in[0];
  const int* ei   = (const int*)d_in[1];
  const float* ea = (const float*)d_in[2];
  const float* c1Wx = (const float*)d_in[3];
  const float* c1We = (const float*)d_in[4];
  const float* c1as = (const float*)d_in[5];
  const float* c1ad = (const float*)d_in[6];
  const float* c1ae = (const float*)d_in[7];
  const float* c1b  = (const float*)d_in[8];
  const float* e1w1 = (const float*)d_in[9];
  const float* e1b1 = (const float*)d_in[10];
  const float* e1w2 = (const float*)d_in[11];
  const float* e1b2 = (const float*)d_in[12];
  const float* e1w3 = (const float*)d_in[13];
  const float* e1b3 = (const float*)d_in[14];
  const float* e1w4 = (const float*)d_in[15];
  const float* e1b4 = (const float*)d_in[16];
  const float* c2Wx = (const float*)d_in[17];
  const float* c2We = (const float*)d_in[18];
  const float* c2as = (const float*)d_in[19];
  const float* c2ad = (const float*)d_in[20];
  const float* c2ae = (const float*)d_in[21];
  const float* c2b  = (const float*)d_in[22];
  const float* nlw1 = (const float*)d_in[23];
  const float* nlb1 = (const float*)d_in[24];
  const float* nlw2 = (const float*)d_in[25];
  const float* nlb2 = (const float*)d_in[26];
  const float* elw1 = (const float*)d_in[27];
  const float* elb1 = (const float*)d_in[28];
  const float* elw2 = (const float*)d_in[29];
  const float* elb2 = (const float*)d_in[30];

  float* ws = (float*)d_ws;
  const size_t N = NN;
  int* off   = (int*)ws;                 // N+1
  int* cnt   = (int*)ws + (N + 4);       // N
  float* h   = ws + 2*N + 8;             // 16N (h1, then h2)
  float* hs  = h  + 16*N;                // N  (hs1, then hs2)
  float* hd  = hs + N;                   // N
  float* x1  = hd + N;                   // 16N
  float* acc = x1 + 16*N;                // 16N
  float* s   = acc + 16*N;               // N
  float* u   = s + N;                    // 32N
  float* v   = u + 32*N;                 // 32N
  float2* edata = (float2*)(v + 32*N);   // NE float2

  float* nout = (float*)d_out;            // [100000, 2]
  float* eout = (float*)d_out + 200000;   // [3200000, 4]

  const int GE = (NE + 255)/256;
  const int GN = (NN + 255)/256;

  hipMemsetAsync(cnt, 0, N*sizeof(int), stream);
  khist<<<GE, 256, 0, stream>>>(ei, cnt);
  kscan<<<1, 1024, 0, stream>>>(cnt, off);          // off = scan(cnt); cnt = 0
  k1<<<GN, 256, 0, stream>>>(x, c1Wx, c1as, c1ad, h, hs, hd);
  k2a<<<GE, 256, 0, stream>>>(ei, ea, c1We, c1ae, hs, hd, off, cnt, edata);
  kagg<<<(NN+15)/16, 256, 0, stream>>>(edata, off, h, acc, s, cnt);   // also re-zeros cnt
  k4<<<GN, 256, 0, stream>>>(acc, s, c1b, c2Wx, c2as, c2ad, e1w1, x1, h, hs, hd, u, v);
  k5<<<GE, 256, 0, stream>>>(ei, ea, u, v, hs, hd,
      e1w1, e1b1, e1w2, e1b2, e1w3, e1b3, e1w4, e1b4,
      c2We, c2ae, elw1, elb1, elw2, elb2,
      off, cnt, edata, eout);
  kagg<<<(NN+15)/16, 256, 0, stream>>>(edata, off, h, acc, s, cnt);
  k7<<<GN, 256, 0, stream>>>(acc, s, c2b, nlw1, nlb1, nlw2, nlb2, nout);
}

// Round 10
// 1099.923 us; speedup vs baseline: 7.6785x; 1.2555x over previous
//
#include <hip/hip_runtime.h>

#define NN 100000
#define NE 3200000

typedef unsigned int u32;
typedef _Float16 f16x2 __attribute__((ext_vector_type(2)));
typedef __fp16 fp16v2 __attribute__((ext_vector_type(2)));

__device__ __forceinline__ int clampi(int s){
  s = s < 0 ? 0 : s;
  return s >= NN ? NN-1 : s;
}

__device__ __forceinline__ f16x2 pk2(float x, float y){
  fp16v2 r = __builtin_amdgcn_cvt_pkrtz(x, y);
  return __builtin_bit_cast(f16x2, r);
}
__device__ __forceinline__ float dot2(f16x2 a, f16x2 b, float c){
  return __builtin_amdgcn_fdot2(a, b, c, false);
}

// dual-accumulator dot (f32, used by k4)
template<int N4>
__device__ __forceinline__ float dotl(const float* __restrict__ a, const float* w){
  float acc0 = 0.f, acc1 = 0.f;
  #pragma unroll
  for (int k = 0; k < N4; k += 2){
    float4 q0 = ((const float4*)w)[k];
    acc0 += a[4*k]*q0.x + a[4*k+1]*q0.y + a[4*k+2]*q0.z + a[4*k+3]*q0.w;
    float4 q1 = ((const float4*)w)[k+1];
    acc1 += a[4*k+4]*q1.x + a[4*k+5]*q1.y + a[4*k+6]*q1.z + a[4*k+7]*q1.w;
  }
  return acc0 + acc1;
}

// ---------------- khist: cnt[d]++ ------------------------------------------
__global__ __launch_bounds__(256,8) void khist(const int* __restrict__ ei, int* __restrict__ cnt){
  int i = blockIdx.x*256 + threadIdx.x;
  if (i >= NE) return;
  atomicAdd(&cnt[clampi(ei[NE+i])], 1);
}

// ---------------- kscan: off = exclusive_scan(cnt); cnt = 0 ----------------
__global__ void kscan(int* __restrict__ cnt, int* __restrict__ off){
  __shared__ int wsum[16];
  __shared__ int carry;
  int tid = threadIdx.x;
  if (tid == 0) carry = 0;
  __syncthreads();
  for (int base = 0; base < NN; base += 1024){
    int i = base + tid;
    int v = (i < NN) ? cnt[i] : 0;
    int x = v;
    #pragma unroll
    for (int ofs = 1; ofs < 64; ofs <<= 1){
      int t = __shfl_up(x, ofs, 64);
      if ((tid & 63) >= ofs) x += t;
    }
    if ((tid & 63) == 63) wsum[tid >> 6] = x;
    __syncthreads();
    if (tid < 16){
      int y = wsum[tid];
      #pragma unroll
      for (int ofs = 1; ofs < 16; ofs <<= 1){
        int t = __shfl_up(y, ofs, 64);
        if (tid >= ofs) y += t;
      }
      wsum[tid] = y;
    }
    __syncthreads();
    int wb = (tid >= 64) ? wsum[(tid >> 6) - 1] : 0;
    int incl = wb + x;
    if (i < NN){ off[i] = carry + incl - v; cnt[i] = 0; }
    int ctot = wsum[15];
    __syncthreads();
    if (tid == 0) carry += ctot;
    __syncthreads();
  }
  if (tid == 0) off[NN] = carry;
}

// ---------------- k1: h1 = x @ c1_Wx^T ; hs1 ; hd1 --------------------------
__global__ __launch_bounds__(256,4) void k1(const float* __restrict__ x,
    const float* __restrict__ Wx, const float* __restrict__ asrc, const float* __restrict__ adst,
    float* __restrict__ h1, float* __restrict__ hs1, float* __restrict__ hd1)
{
  __shared__ float wL[64], aS[16], aD[16];
  int tid = threadIdx.x;
  if (tid < 64) wL[tid] = Wx[tid];
  if (tid < 16){ aS[tid] = asrc[tid]; aD[tid] = adst[tid]; }
  __syncthreads();
  int n = blockIdx.x*256 + tid;
  if (n >= NN) return;
  float4 xr = ((const float4*)x)[n];
  float hs=0.f, hd=0.f;
  float* hrow = h1 + (size_t)n*16;
  #pragma unroll
  for (int j=0;j<16;j++){
    float h = xr.x*wL[j*4+0] + xr.y*wL[j*4+1] + xr.z*wL[j*4+2] + xr.w*wL[j*4+3];
    hrow[j] = h; hs += h*aS[j]; hd += h*aD[j];
  }
  hs1[n]=hs; hd1[n]=hd;
}

// ---------------- k2a: alpha1 -> scatter (ex, src) into CSR slot ------------
__global__ __launch_bounds__(256,8) void k2a(const int* __restrict__ ei,
    const float* __restrict__ ea, const float* __restrict__ We, const float* __restrict__ aedge,
    const float* __restrict__ hs1, const float* __restrict__ hd1,
    const int* __restrict__ off, int* __restrict__ cnt, float2* __restrict__ edata)
{
  __shared__ float w6[6];
  int tid = threadIdx.x;
  if (tid < 6){
    float acc = 0.f;
    for (int j=0;j<16;j++) acc += aedge[j] * We[j*6+tid];
    w6[tid] = acc;
  }
  __syncthreads();
  int i = blockIdx.x*256 + tid;
  if (i >= NE) return;
  int s = clampi(ei[i]);
  int d = clampi(ei[NE + i]);
  const float2* eap = (const float2*)ea + (size_t)i*3;
  float2 u0 = eap[0], u1 = eap[1], u2 = eap[2];
  float al = hs1[s] + hd1[d]
    + u0.x*w6[0] + u0.y*w6[1] + u1.x*w6[2]
    + u1.y*w6[3] + u2.x*w6[4] + u2.y*w6[5];
  al = al > 0.f ? al : 0.2f*al;
  float ex = __expf(al);
  int pos = off[d] + atomicAdd(&cnt[d], 1);
  edata[pos] = make_float2(ex, __int_as_float(s));
}

// ---------------- kagg: per-node CSR reduce (16 lanes = 16 features) --------
__global__ __launch_bounds__(256,4) void kagg(const float2* __restrict__ edata,
    const int* __restrict__ off, const float* __restrict__ h,
    float* __restrict__ acc, float* __restrict__ s, int* __restrict__ cnt)
{
  int n = (blockIdx.x*256 + threadIdx.x) >> 4;
  int j = threadIdx.x & 15;
  if (n >= NN) return;
  int beg = off[n], end = off[n+1];
  float aj = 0.f, sl = 0.f;
  for (int k = beg; k < end; ++k){
    float2 p = edata[k];
    int src = __float_as_int(p.y);
    aj += p.x * h[(size_t)src*16 + j];
    sl += p.x;
  }
  acc[(size_t)n*16 + j] = aj;
  if (j == 0){ s[n] = sl; cnt[n] = 0; }
}

// ---------------- k4: x1 = acc/s + b1 ; h2 ; hs2 ; hd2 ; u = W1s.x1 ; v = W1d.x1
__global__ __launch_bounds__(256,2) void k4(const float* __restrict__ accb,
    const float* __restrict__ sb, const float* __restrict__ c1b, const float* __restrict__ Wx2,
    const float* __restrict__ a2s, const float* __restrict__ a2d,
    const float* __restrict__ w1p,
    float* __restrict__ x1, float* __restrict__ h2,
    float* __restrict__ hs2, float* __restrict__ hd2,
    float* __restrict__ u, float* __restrict__ v)
{
  __shared__ float wL[256], bL[16], aS[16], aD[16];
  __shared__ float w1sL[32*16], w1dL[32*16];
  int tid = threadIdx.x;
  wL[tid] = Wx2[tid];
  if (tid < 16){ bL[tid]=c1b[tid]; aS[tid]=a2s[tid]; aD[tid]=a2d[tid]; }
  for (int idx=tid; idx<512; idx+=256){
    int j=idx>>4, k=idx&15;
    w1sL[idx] = w1p[j*38+k];
    w1dL[idx] = w1p[j*38+22+k];
  }
  __syncthreads();
  int n = blockIdx.x*256 + tid;
  if (n >= NN) return;
  float inv = 1.f/(sb[n] + 1e-16f);
  float xv[16];
  const float* xp = accb + (size_t)n*16;
  float* x1r = x1 + (size_t)n*16;
  #pragma unroll
  for (int j=0;j<16;j++){ xv[j] = xp[j]*inv + bL[j]; x1r[j] = xv[j]; }
  float hs=0.f, hd=0.f;
  float* h2r = h2 + (size_t)n*16;
  #pragma unroll
  for (int j=0;j<16;j++){
    float acc = 0.f;
    #pragma unroll
    for (int k=0;k<16;k++) acc += xv[k]*wL[j*16+k];
    h2r[j] = acc; hs += acc*aS[j]; hd += acc*aD[j];
  }
  hs2[n]=hs; hd2[n]=hd;
  float* ur = u + (size_t)n*32;
  float* vr = v + (size_t)n*32;
  #pragma unroll
  for (int j=0;j<32;j++){
    ur[j] = dotl<4>(xv, &w1sL[j*16]);
    vr[j] = dotl<4>(xv, &w1dL[j*16]);
  }
}

// ---------------- k5: edge MLP (f16 dot2) + edge head + alpha2 scatter ------
// r8 structure (known-good) with all GEMV weights packed half2 in LDS and
// v_dot2_f32_f16 (2 MACs/instr, f32 accum). Activations packed via cvt_pkrtz.
__global__ __launch_bounds__(256,3) void k5(
    const int* __restrict__ ei, const float* __restrict__ ea,
    const float* __restrict__ u, const float* __restrict__ v,
    const float* __restrict__ hs2, const float* __restrict__ hd2,
    const float* w1p, const float* b1p, const float* w2p, const float* b2p,
    const float* w3p, const float* b3p, const float* w4p, const float* b4p,
    const float* We2, const float* a2e,
    const float* ew1p, const float* eb1p, const float* ew2p, const float* eb2p,
    const int* __restrict__ off, int* __restrict__ cnt, float2* __restrict__ edata,
    float* __restrict__ eout)
{
  __shared__ __align__(16) f16x2 w1eh[32*4];  __shared__ float b1L[32];
  __shared__ __align__(16) f16x2 w2h[64*16];  __shared__ float b2L[64];
  __shared__ __align__(16) f16x2 w3h[32*32];  __shared__ float b3L[32];
  __shared__ __align__(16) f16x2 w4h[16*16];  __shared__ float b4L[16];
  __shared__ __align__(16) f16x2 ew1h[16*8];  __shared__ float eb1L[16];
  __shared__ __align__(16) f16x2 ew2h[4*8];   __shared__ float eb2L[4];
  __shared__ __align__(16) f16x2 w16h[8];
  int tid = threadIdx.x;
  if (tid < 128){
    int j=tid>>2, kk=tid&3;
    int k0=2*kk, k1=2*kk+1;
    float v0 = (k0<6) ? w1p[j*38+16+k0] : 0.f;
    float v1 = (k1<6) ? w1p[j*38+16+k1] : 0.f;
    w1eh[tid] = pk2(v0, v1);
  }
  for (int idx=tid; idx<1024; idx+=256){
    int j=idx>>4, kk=idx&15;
    w2h[idx] = pk2(w2p[j*32+2*kk], w2p[j*32+2*kk+1]);
  }
  for (int idx=tid; idx<1024; idx+=256){
    int j=idx>>5, kk=idx&31;
    w3h[idx] = pk2(w3p[j*64+2*kk], w3p[j*64+2*kk+1]);
  }
  if (tid < 256){
    int j=tid>>4, kk=tid&15;
    w4h[tid] = pk2(w4p[j*32+2*kk], w4p[j*32+2*kk+1]);
  }
  if (tid < 128){
    int j=tid>>3, kk=tid&7;
    ew1h[tid] = pk2(ew1p[j*16+2*kk], ew1p[j*16+2*kk+1]);
  }
  if (tid < 32){
    int j=tid>>3, kk=tid&7;
    ew2h[tid] = pk2(ew2p[j*16+2*kk], ew2p[j*16+2*kk+1]);
  }
  if (tid < 8){
    float s0=0.f, s1=0.f;
    for (int j=0;j<16;j++){
      s0 += a2e[j] * We2[j*16 + 2*tid];
      s1 += a2e[j] * We2[j*16 + 2*tid + 1];
    }
    w16h[tid] = pk2(s0, s1);
  }
  if (tid < 64) b2L[tid] = b2p[tid];
  if (tid < 32){ b1L[tid] = b1p[tid]; b3L[tid] = b3p[tid]; }
  if (tid < 16){ b4L[tid] = b4p[tid]; eb1L[tid] = eb1p[tid]; }
  if (tid < 4)  eb2L[tid] = eb2p[tid];
  __syncthreads();

  int i = blockIdx.x*256 + tid;
  if (i >= NE) return;
  int s = clampi(ei[i]);
  int d = clampi(ei[NE + i]);

  // ---- layer 1: a1 = relu(u[s] + v[d] + W1e.ea + b1), packed to f16x2 ----
  f16x2 a1h[16];
  {
    const float2* eap = (const float2*)ea + (size_t)i*3;
    float2 e0=eap[0], e1=eap[1], e2=eap[2];
    f16x2 eh[4];
    eh[0]=pk2(e0.x,e0.y); eh[1]=pk2(e1.x,e1.y); eh[2]=pk2(e2.x,e2.y); eh[3]=pk2(0.f,0.f);
    const float4* up = (const float4*)(u + (size_t)s*32);
    const float4* vp = (const float4*)(v + (size_t)d*32);
    #pragma unroll
    for (int q=0;q<8;q++){
      float4 uq = up[q];
      float4 vq = vp[q];
      float r0 = uq.x + vq.x + b1L[4*q+0];
      float r1 = uq.y + vq.y + b1L[4*q+1];
      float r2 = uq.z + vq.z + b1L[4*q+2];
      float r3 = uq.w + vq.w + b1L[4*q+3];
      #pragma unroll
      for (int kk=0;kk<4;kk++){
        r0 = dot2(eh[kk], w1eh[(4*q+0)*4+kk], r0);
        r1 = dot2(eh[kk], w1eh[(4*q+1)*4+kk], r1);
        r2 = dot2(eh[kk], w1eh[(4*q+2)*4+kk], r2);
        r3 = dot2(eh[kk], w1eh[(4*q+3)*4+kk], r3);
      }
      a1h[2*q]   = pk2(fmaxf(r0,0.f), fmaxf(r1,0.f));
      a1h[2*q+1] = pk2(fmaxf(r2,0.f), fmaxf(r3,0.f));
    }
  }
  // ---- layer 2: 32 -> 64 ----
  f16x2 a2h[32];
  #pragma unroll
  for (int j=0;j<32;j++){
    float acc0 = b2L[2*j], acc1 = b2L[2*j+1];
    #pragma unroll
    for (int kk=0;kk<16;kk++){
      acc0 = dot2(a1h[kk], w2h[(2*j)*16+kk],   acc0);
      acc1 = dot2(a1h[kk], w2h[(2*j+1)*16+kk], acc1);
    }
    a2h[j] = pk2(fmaxf(acc0,0.f), fmaxf(acc1,0.f));
  }
  // ---- layer 3: 64 -> 32 ----
  f16x2 a3h[16];
  #pragma unroll
  for (int j=0;j<16;j++){
    float acc0 = b3L[2*j], acc1 = b3L[2*j+1];
    #pragma unroll
    for (int kk=0;kk<32;kk++){
      acc0 = dot2(a2h[kk], w3h[(2*j)*32+kk],   acc0);
      acc1 = dot2(a2h[kk], w3h[(2*j+1)*32+kk], acc1);
    }
    a3h[j] = pk2(fmaxf(acc0,0.f), fmaxf(acc1,0.f));
  }
  // ---- layer 4: 32 -> 16 (no relu) ----
  f16x2 eh4[8];
  #pragma unroll
  for (int j=0;j<8;j++){
    float acc0 = b4L[2*j], acc1 = b4L[2*j+1];
    #pragma unroll
    for (int kk=0;kk<16;kk++){
      acc0 = dot2(a3h[kk], w4h[(2*j)*16+kk],   acc0);
      acc1 = dot2(a3h[kk], w4h[(2*j+1)*16+kk], acc1);
    }
    eh4[j] = pk2(acc0, acc1);
  }
  // ---- edge head + log_softmax(4) ----
  f16x2 th[8];
  #pragma unroll
  for (int j=0;j<8;j++){
    float acc0 = eb1L[2*j], acc1 = eb1L[2*j+1];
    #pragma unroll
    for (int kk=0;kk<8;kk++){
      acc0 = dot2(eh4[kk], ew1h[(2*j)*8+kk],   acc0);
      acc1 = dot2(eh4[kk], ew1h[(2*j+1)*8+kk], acc1);
    }
    th[j] = pk2(fmaxf(acc0,0.f), fmaxf(acc1,0.f));
  }
  float y0 = eb2L[0], y1 = eb2L[1], y2 = eb2L[2], y3 = eb2L[3];
  #pragma unroll
  for (int kk=0;kk<8;kk++){
    y0 = dot2(th[kk], ew2h[0*8+kk], y0);
    y1 = dot2(th[kk], ew2h[1*8+kk], y1);
    y2 = dot2(th[kk], ew2h[2*8+kk], y2);
    y3 = dot2(th[kk], ew2h[3*8+kk], y3);
  }
  y0 = fmaxf(y0,0.f); y1 = fmaxf(y1,0.f); y2 = fmaxf(y2,0.f); y3 = fmaxf(y3,0.f);
  float m = fmaxf(fmaxf(y0,y1), fmaxf(y2,y3));
  float l = m + __logf(__expf(y0-m)+__expf(y1-m)+__expf(y2-m)+__expf(y3-m));
  float4 eo; eo.x = y0-l; eo.y = y1-l; eo.z = y2-l; eo.w = y3-l;
  ((float4*)eout)[i] = eo;

  // ---- conv2 alpha -> CSR scatter ----
  float al = hs2[s] + hd2[d];
  #pragma unroll
  for (int kk=0;kk<8;kk++) al = dot2(eh4[kk], w16h[kk], al);
  al = al > 0.f ? al : 0.2f*al;
  float ex = __expf(al);
  int pos = off[d] + atomicAdd(&cnt[d], 1);
  edata[pos] = make_float2(ex, __int_as_float(s));
}

// ---------------- k7: x2 -> node head -> log_softmax(2) --------------------
__global__ __launch_bounds__(256,4) void k7(const float* __restrict__ accb,
    const float* __restrict__ sb, const float* __restrict__ c2b,
    const float* __restrict__ w1p, const float* __restrict__ b1p,
    const float* __restrict__ w2p, const float* __restrict__ b2p,
    float* __restrict__ nout)
{
  __shared__ float wL[256], bL[16], w2L[32], b2L[2], cb[16];
  int tid = threadIdx.x;
  wL[tid] = w1p[tid];
  if (tid < 16){ bL[tid]=b1p[tid]; cb[tid]=c2b[tid]; }
  if (tid < 32) w2L[tid] = w2p[tid];
  if (tid < 2)  b2L[tid] = b2p[tid];
  __syncthreads();
  int n = blockIdx.x*256 + tid;
  if (n >= NN) return;
  float inv = 1.f/(sb[n] + 1e-16f);
  const float* xp = accb + (size_t)n*16;
  float v[16];
  #pragma unroll
  for (int j=0;j<16;j++) v[j] = xp[j]*inv + cb[j];
  float t[16];
  #pragma unroll
  for (int j=0;j<16;j++){
    float acc = bL[j];
    #pragma unroll
    for (int k=0;k<16;k++) acc += v[k]*wL[j*16+k];
    t[j] = fmaxf(acc, 0.f);
  }
  float y0 = b2L[0], y1 = b2L[1];
  #pragma unroll
  for (int k=0;k<16;k++){ y0 += t[k]*w2L[k]; y1 += t[k]*w2L[16+k]; }
  y0 = fmaxf(y0, 0.f); y1 = fmaxf(y1, 0.f);
  float m = fmaxf(y0, y1);
  float l = m + __logf(__expf(y0-m) + __expf(y1-m));
  float2 no; no.x = y0-l; no.y = y1-l;
  ((float2*)nout)[n] = no;
}

extern "C" void kernel_launch(void* const* d_in, const int* in_sizes, int n_in,
                              void* d_out, int out_size, void* d_ws, size_t ws_size,
                              hipStream_t stream)
{
  const float* x  = (const float*)d_in[0];
  const int* ei   = (const int*)d_in[1];
  const float* ea = (const float*)d_in[2];
  const float* c1Wx = (const float*)d_in[3];
  const float* c1We = (const float*)d_in[4];
  const float* c1as = (const float*)d_in[5];
  const float* c1ad = (const float*)d_in[6];
  const float* c1ae = (const float*)d_in[7];
  const float* c1b  = (const float*)d_in[8];
  const float* e1w1 = (const float*)d_in[9];
  const float* e1b1 = (const float*)d_in[10];
  const float* e1w2 = (const float*)d_in[11];
  const float* e1b2 = (const float*)d_in[12];
  const float* e1w3 = (const float*)d_in[13];
  const float* e1b3 = (const float*)d_in[14];
  const float* e1w4 = (const float*)d_in[15];
  const float* e1b4 = (const float*)d_in[16];
  const float* c2Wx = (const float*)d_in[17];
  const float* c2We = (const float*)d_in[18];
  const float* c2as = (const float*)d_in[19];
  const float* c2ad = (const float*)d_in[20];
  const float* c2ae = (const float*)d_in[21];
  const float* c2b  = (const float*)d_in[22];
  const float* nlw1 = (const float*)d_in[23];
  const float* nlb1 = (const float*)d_in[24];
  const float* nlw2 = (const float*)d_in[25];
  const float* nlb2 = (const float*)d_in[26];
  const float* elw1 = (const float*)d_in[27];
  const float* elb1 = (const float*)d_in[28];
  const float* elw2 = (const float*)d_in[29];
  const float* elb2 = (const float*)d_in[30];

  float* ws = (float*)d_ws;
  const size_t N = NN;
  int* off   = (int*)ws;                 // N+1
  int* cnt   = (int*)ws + (N + 4);       // N
  float* h   = ws + 2*N + 8;             // 16N (h1, then h2)
  float* hs  = h  + 16*N;                // N  (hs1, then hs2)
  float* hd  = hs + N;                   // N
  float* x1  = hd + N;                   // 16N
  float* acc = x1 + 16*N;                // 16N
  float* s   = acc + 16*N;               // N
  float* u   = s + N;                    // 32N
  float* v   = u + 32*N;                 // 32N
  float2* edata = (float2*)(v + 32*N);   // NE float2

  float* nout = (float*)d_out;            // [100000, 2]
  float* eout = (float*)d_out + 200000;   // [3200000, 4]

  const int GE = (NE + 255)/256;
  const int GN = (NN + 255)/256;

  (void)hipMemsetAsync(cnt, 0, N*sizeof(int), stream);
  khist<<<GE, 256, 0, stream>>>(ei, cnt);
  kscan<<<1, 1024, 0, stream>>>(cnt, off);          // off = scan(cnt); cnt = 0
  k1<<<GN, 256, 0, stream>>>(x, c1Wx, c1as, c1ad, h, hs, hd);
  k2a<<<GE, 256, 0, stream>>>(ei, ea, c1We, c1ae, hs, hd, off, cnt, edata);
  kagg<<<(NN+15)/16, 256, 0, stream>>>(edata, off, h, acc, s, cnt);   // also re-zeros cnt
  k4<<<GN, 256, 0, stream>>>(acc, s, c1b, c2Wx, c2as, c2ad, e1w1, x1, h, hs, hd, u, v);
  k5<<<GE, 256, 0, stream>>>(ei, ea, u, v, hs, hd,
      e1w1, e1b1, e1w2, e1b2, e1w3, e1b3, e1w4, e1b4,
      c2We, c2ae, elw1, elb1, elw2, elb2,
      off, cnt, edata, eout);
  kagg<<<(NN+15)/16, 256, 0, stream>>>(edata, off, h, acc, s, cnt);
  k7<<<GN, 256, 0, stream>>>(acc, s, c2b, nlw1, nlb1, nlw2, nlb2, nout);
}

// Round 11
// 987.191 us; speedup vs baseline: 8.5554x; 1.1142x over previous
//
#include <hip/hip_runtime.h>

#define NN 100000
#define NE 3200000
#define NB 98   // ceil(NN/1024)

typedef unsigned int u32;
typedef _Float16 f16x2 __attribute__((ext_vector_type(2)));
typedef __fp16 fp16v2 __attribute__((ext_vector_type(2)));

__device__ __forceinline__ int clampi(int s){
  s = s < 0 ? 0 : s;
  return s >= NN ? NN-1 : s;
}

__device__ __forceinline__ f16x2 pk2(float x, float y){
  fp16v2 r = __builtin_amdgcn_cvt_pkrtz(x, y);
  return __builtin_bit_cast(f16x2, r);
}
__device__ __forceinline__ float dot2(f16x2 a, f16x2 b, float c){
  return __builtin_amdgcn_fdot2(a, b, c, false);
}
__device__ __forceinline__ float f16lo(u32 w){
  __fp16 h = __builtin_bit_cast(__fp16, (unsigned short)(w & 0xffffu));
  return (float)h;
}
__device__ __forceinline__ float f16hi(u32 w){
  __fp16 h = __builtin_bit_cast(__fp16, (unsigned short)(w >> 16));
  return (float)h;
}

// dual-accumulator dot (f32, used by k4)
template<int N4>
__device__ __forceinline__ float dotl(const float* __restrict__ a, const float* w){
  float acc0 = 0.f, acc1 = 0.f;
  #pragma unroll
  for (int k = 0; k < N4; k += 2){
    float4 q0 = ((const float4*)w)[k];
    acc0 += a[4*k]*q0.x + a[4*k+1]*q0.y + a[4*k+2]*q0.z + a[4*k+3]*q0.w;
    float4 q1 = ((const float4*)w)[k+1];
    acc1 += a[4*k+4]*q1.x + a[4*k+5]*q1.y + a[4*k+6]*q1.z + a[4*k+7]*q1.w;
  }
  return acc0 + acc1;
}

// ---------------- khist: cnt[d]++ ------------------------------------------
__global__ __launch_bounds__(256,8) void khist(const int* __restrict__ ei, int* __restrict__ cnt){
  int i = blockIdx.x*256 + threadIdx.x;
  if (i >= NE) return;
  atomicAdd(&cnt[clampi(ei[NE+i])], 1);
}

// ---------------- kscanA: per-block sums of cnt -----------------------------
__global__ __launch_bounds__(1024) void kscanA(const int* __restrict__ cnt, int* __restrict__ bsum){
  __shared__ int wsum[16];
  int tid = threadIdx.x;
  int i = blockIdx.x*1024 + tid;
  int x = (i < NN) ? cnt[i] : 0;
  #pragma unroll
  for (int ofs = 1; ofs < 64; ofs <<= 1) x += __shfl_xor(x, ofs, 64);
  if ((tid & 63) == 0) wsum[tid >> 6] = x;
  __syncthreads();
  if (tid == 0){
    int t = 0;
    #pragma unroll
    for (int k = 0; k < 16; k++) t += wsum[k];
    bsum[blockIdx.x] = t;
  }
}

// ---------------- kscanB: scan the 98 block sums ----------------------------
__global__ void kscanB(const int* __restrict__ bsum, int* __restrict__ boff, int* __restrict__ offN){
  if (threadIdx.x == 0){
    int c = 0;
    for (int b = 0; b < NB; b++){ boff[b] = c; c += bsum[b]; }
    offN[0] = c;
  }
}

// ---------------- kscanC: block-local scan + offset; cnt = 0 ----------------
__global__ __launch_bounds__(1024) void kscanC(int* __restrict__ cnt, const int* __restrict__ boff,
                                               int* __restrict__ off){
  __shared__ int wsum[16];
  int tid = threadIdx.x;
  int i = blockIdx.x*1024 + tid;
  int v = (i < NN) ? cnt[i] : 0;
  int x = v;
  #pragma unroll
  for (int ofs = 1; ofs < 64; ofs <<= 1){
    int t = __shfl_up(x, ofs, 64);
    if ((tid & 63) >= ofs) x += t;
  }
  if ((tid & 63) == 63) wsum[tid >> 6] = x;
  __syncthreads();
  if (tid < 16){
    int y = wsum[tid];
    #pragma unroll
    for (int ofs = 1; ofs < 16; ofs <<= 1){
      int t = __shfl_up(y, ofs, 64);
      if (tid >= ofs) y += t;
    }
    wsum[tid] = y;
  }
  __syncthreads();
  int wb = (tid >= 64) ? wsum[(tid >> 6) - 1] : 0;
  if (i < NN){ off[i] = boff[blockIdx.x] + wb + x - v; cnt[i] = 0; }
}

// ---------------- k1: h1 = x @ c1_Wx^T ; hs1 ; hd1 --------------------------
__global__ __launch_bounds__(256,4) void k1(const float* __restrict__ x,
    const float* __restrict__ Wx, const float* __restrict__ asrc, const float* __restrict__ adst,
    float* __restrict__ h1, float* __restrict__ hs1, float* __restrict__ hd1)
{
  __shared__ float wL[64], aS[16], aD[16];
  int tid = threadIdx.x;
  if (tid < 64) wL[tid] = Wx[tid];
  if (tid < 16){ aS[tid] = asrc[tid]; aD[tid] = adst[tid]; }
  __syncthreads();
  int n = blockIdx.x*256 + tid;
  if (n >= NN) return;
  float4 xr = ((const float4*)x)[n];
  float hs=0.f, hd=0.f;
  float* hrow = h1 + (size_t)n*16;
  #pragma unroll
  for (int j=0;j<16;j++){
    float h = xr.x*wL[j*4+0] + xr.y*wL[j*4+1] + xr.z*wL[j*4+2] + xr.w*wL[j*4+3];
    hrow[j] = h; hs += h*aS[j]; hd += h*aD[j];
  }
  hs1[n]=hs; hd1[n]=hd;
}

// ---------------- k2a: alpha1 -> scatter (ex, src) into CSR slot ------------
__global__ __launch_bounds__(256,8) void k2a(const int* __restrict__ ei,
    const float* __restrict__ ea, const float* __restrict__ We, const float* __restrict__ aedge,
    const float* __restrict__ hs1, const float* __restrict__ hd1,
    const int* __restrict__ off, int* __restrict__ cnt, float2* __restrict__ edata)
{
  __shared__ float w6[6];
  int tid = threadIdx.x;
  if (tid < 6){
    float acc = 0.f;
    for (int j=0;j<16;j++) acc += aedge[j] * We[j*6+tid];
    w6[tid] = acc;
  }
  __syncthreads();
  int i = blockIdx.x*256 + tid;
  if (i >= NE) return;
  int s = clampi(ei[i]);
  int d = clampi(ei[NE + i]);
  const float2* eap = (const float2*)ea + (size_t)i*3;
  float2 u0 = eap[0], u1 = eap[1], u2 = eap[2];
  float al = hs1[s] + hd1[d]
    + u0.x*w6[0] + u0.y*w6[1] + u1.x*w6[2]
    + u1.y*w6[3] + u2.x*w6[4] + u2.y*w6[5];
  al = al > 0.f ? al : 0.2f*al;
  float ex = __expf(al);
  int pos = off[d] + atomicAdd(&cnt[d], 1);
  edata[pos] = make_float2(ex, __int_as_float(s));
}

// ---------------- kagg: per-node CSR reduce (16 lanes = 16 features) --------
__global__ __launch_bounds__(256,4) void kagg(const float2* __restrict__ edata,
    const int* __restrict__ off, const float* __restrict__ h,
    float* __restrict__ acc, float* __restrict__ s, int* __restrict__ cnt)
{
  int n = (blockIdx.x*256 + threadIdx.x) >> 4;
  int j = threadIdx.x & 15;
  if (n >= NN) return;
  int beg = off[n], end = off[n+1];
  float aj = 0.f, sl = 0.f;
  for (int k = beg; k < end; ++k){
    float2 p = edata[k];
    int src = __float_as_int(p.y);
    aj += p.x * h[(size_t)src*16 + j];
    sl += p.x;
  }
  acc[(size_t)n*16 + j] = aj;
  if (j == 0){ s[n] = sl; cnt[n] = 0; }
}

// ---------------- k4: x1 = acc/s + b1 ; h2 ; hs2 ; hd2 ; u,v packed f16 -----
__global__ __launch_bounds__(256,2) void k4(const float* __restrict__ accb,
    const float* __restrict__ sb, const float* __restrict__ c1b, const float* __restrict__ Wx2,
    const float* __restrict__ a2s, const float* __restrict__ a2d,
    const float* __restrict__ w1p,
    float* __restrict__ h2,
    float* __restrict__ hs2, float* __restrict__ hd2,
    u32* __restrict__ uh, u32* __restrict__ vh)
{
  __shared__ float wL[256], bL[16], aS[16], aD[16];
  __shared__ float w1sL[32*16], w1dL[32*16];
  int tid = threadIdx.x;
  wL[tid] = Wx2[tid];
  if (tid < 16){ bL[tid]=c1b[tid]; aS[tid]=a2s[tid]; aD[tid]=a2d[tid]; }
  for (int idx=tid; idx<512; idx+=256){
    int j=idx>>4, k=idx&15;
    w1sL[idx] = w1p[j*38+k];
    w1dL[idx] = w1p[j*38+22+k];
  }
  __syncthreads();
  int n = blockIdx.x*256 + tid;
  if (n >= NN) return;
  float inv = 1.f/(sb[n] + 1e-16f);
  float xv[16];
  const float* xp = accb + (size_t)n*16;
  #pragma unroll
  for (int j=0;j<16;j++) xv[j] = xp[j]*inv + bL[j];
  float hs=0.f, hd=0.f;
  float* h2r = h2 + (size_t)n*16;
  #pragma unroll
  for (int j=0;j<16;j++){
    float acc = 0.f;
    #pragma unroll
    for (int k=0;k<16;k++) acc += xv[k]*wL[j*16+k];
    h2r[j] = acc; hs += acc*aS[j]; hd += acc*aD[j];
  }
  hs2[n]=hs; hd2[n]=hd;
  u32* ur = uh + (size_t)n*16;
  u32* vr = vh + (size_t)n*16;
  #pragma unroll
  for (int j=0;j<16;j++){
    float u0 = dotl<4>(xv, &w1sL[(2*j)*16]);
    float u1 = dotl<4>(xv, &w1sL[(2*j+1)*16]);
    ur[j] = __builtin_bit_cast(u32, pk2(u0, u1));
    float v0 = dotl<4>(xv, &w1dL[(2*j)*16]);
    float v1 = dotl<4>(xv, &w1dL[(2*j+1)*16]);
    vr[j] = __builtin_bit_cast(u32, pk2(v0, v1));
  }
}

// ---------------- k5: edge MLP (f16 dot2) + edge head + alpha2 scatter ------
// u/v gathers are f16-packed: 64B/row (r10: 128B f32 rows -> FETCH 950MB,
// gather-latency-bound at VALU 51% / HBM 29%).
__global__ __launch_bounds__(256,3) void k5(
    const int* __restrict__ ei, const float* __restrict__ ea,
    const u32* __restrict__ uh, const u32* __restrict__ vh,
    const float* __restrict__ hs2, const float* __restrict__ hd2,
    const float* w1p, const float* b1p, const float* w2p, const float* b2p,
    const float* w3p, const float* b3p, const float* w4p, const float* b4p,
    const float* We2, const float* a2e,
    const float* ew1p, const float* eb1p, const float* ew2p, const float* eb2p,
    const int* __restrict__ off, int* __restrict__ cnt, float2* __restrict__ edata,
    float* __restrict__ eout)
{
  __shared__ __align__(16) f16x2 w1eh[32*4];  __shared__ float b1L[32];
  __shared__ __align__(16) f16x2 w2h[64*16];  __shared__ float b2L[64];
  __shared__ __align__(16) f16x2 w3h[32*32];  __shared__ float b3L[32];
  __shared__ __align__(16) f16x2 w4h[16*16];  __shared__ float b4L[16];
  __shared__ __align__(16) f16x2 ew1h[16*8];  __shared__ float eb1L[16];
  __shared__ __align__(16) f16x2 ew2h[4*8];   __shared__ float eb2L[4];
  __shared__ __align__(16) f16x2 w16h[8];
  int tid = threadIdx.x;
  if (tid < 128){
    int j=tid>>2, kk=tid&3;
    int k0=2*kk, k1=2*kk+1;
    float v0 = (k0<6) ? w1p[j*38+16+k0] : 0.f;
    float v1 = (k1<6) ? w1p[j*38+16+k1] : 0.f;
    w1eh[tid] = pk2(v0, v1);
  }
  for (int idx=tid; idx<1024; idx+=256){
    int j=idx>>4, kk=idx&15;
    w2h[idx] = pk2(w2p[j*32+2*kk], w2p[j*32+2*kk+1]);
  }
  for (int idx=tid; idx<1024; idx+=256){
    int j=idx>>5, kk=idx&31;
    w3h[idx] = pk2(w3p[j*64+2*kk], w3p[j*64+2*kk+1]);
  }
  if (tid < 256){
    int j=tid>>4, kk=tid&15;
    w4h[tid] = pk2(w4p[j*32+2*kk], w4p[j*32+2*kk+1]);
  }
  if (tid < 128){
    int j=tid>>3, kk=tid&7;
    ew1h[tid] = pk2(ew1p[j*16+2*kk], ew1p[j*16+2*kk+1]);
  }
  if (tid < 32){
    int j=tid>>3, kk=tid&7;
    ew2h[tid] = pk2(ew2p[j*16+2*kk], ew2p[j*16+2*kk+1]);
  }
  if (tid < 8){
    float s0=0.f, s1=0.f;
    for (int j=0;j<16;j++){
      s0 += a2e[j] * We2[j*16 + 2*tid];
      s1 += a2e[j] * We2[j*16 + 2*tid + 1];
    }
    w16h[tid] = pk2(s0, s1);
  }
  if (tid < 64) b2L[tid] = b2p[tid];
  if (tid < 32){ b1L[tid] = b1p[tid]; b3L[tid] = b3p[tid]; }
  if (tid < 16){ b4L[tid] = b4p[tid]; eb1L[tid] = eb1p[tid]; }
  if (tid < 4)  eb2L[tid] = eb2p[tid];
  __syncthreads();

  int i = blockIdx.x*256 + tid;
  if (i >= NE) return;
  int s = clampi(ei[i]);
  int d = clampi(ei[NE + i]);

  // ---- layer 1: a1 = relu(u[s] + v[d] + W1e.ea + b1) ----
  f16x2 a1h[16];
  {
    const float2* eap = (const float2*)ea + (size_t)i*3;
    float2 e0=eap[0], e1=eap[1], e2=eap[2];
    f16x2 eh[4];
    eh[0]=pk2(e0.x,e0.y); eh[1]=pk2(e1.x,e1.y); eh[2]=pk2(e2.x,e2.y); eh[3]=pk2(0.f,0.f);
    const uint4* up = (const uint4*)(uh + (size_t)s*16);
    const uint4* vp = (const uint4*)(vh + (size_t)d*16);
    uint4 U[4], V[4];
    #pragma unroll
    for (int q=0;q<4;q++){ U[q]=up[q]; V[q]=vp[q]; }
    u32 uw[16], vw[16];
    #pragma unroll
    for (int q=0;q<4;q++){
      uw[4*q]=U[q].x; uw[4*q+1]=U[q].y; uw[4*q+2]=U[q].z; uw[4*q+3]=U[q].w;
      vw[4*q]=V[q].x; vw[4*q+1]=V[q].y; vw[4*q+2]=V[q].z; vw[4*q+3]=V[q].w;
    }
    #pragma unroll
    for (int j=0;j<16;j++){
      float t0 = b1L[2*j]   + f16lo(uw[j]) + f16lo(vw[j]);
      float t1 = b1L[2*j+1] + f16hi(uw[j]) + f16hi(vw[j]);
      #pragma unroll
      for (int kk=0;kk<4;kk++){
        t0 = dot2(eh[kk], w1eh[(2*j)*4+kk],   t0);
        t1 = dot2(eh[kk], w1eh[(2*j+1)*4+kk], t1);
      }
      a1h[j] = pk2(fmaxf(t0,0.f), fmaxf(t1,0.f));
    }
  }
  // ---- layer 2: 32 -> 64 ----
  f16x2 a2h[32];
  #pragma unroll
  for (int j=0;j<32;j++){
    float acc0 = b2L[2*j], acc1 = b2L[2*j+1];
    #pragma unroll
    for (int kk=0;kk<16;kk++){
      acc0 = dot2(a1h[kk], w2h[(2*j)*16+kk],   acc0);
      acc1 = dot2(a1h[kk], w2h[(2*j+1)*16+kk], acc1);
    }
    a2h[j] = pk2(fmaxf(acc0,0.f), fmaxf(acc1,0.f));
  }
  // ---- layer 3: 64 -> 32 ----
  f16x2 a3h[16];
  #pragma unroll
  for (int j=0;j<16;j++){
    float acc0 = b3L[2*j], acc1 = b3L[2*j+1];
    #pragma unroll
    for (int kk=0;kk<32;kk++){
      acc0 = dot2(a2h[kk], w3h[(2*j)*32+kk],   acc0);
      acc1 = dot2(a2h[kk], w3h[(2*j+1)*32+kk], acc1);
    }
    a3h[j] = pk2(fmaxf(acc0,0.f), fmaxf(acc1,0.f));
  }
  // ---- layer 4: 32 -> 16 (no relu) ----
  f16x2 eh4[8];
  #pragma unroll
  for (int j=0;j<8;j++){
    float acc0 = b4L[2*j], acc1 = b4L[2*j+1];
    #pragma unroll
    for (int kk=0;kk<16;kk++){
      acc0 = dot2(a3h[kk], w4h[(2*j)*16+kk],   acc0);
      acc1 = dot2(a3h[kk], w4h[(2*j+1)*16+kk], acc1);
    }
    eh4[j] = pk2(acc0, acc1);
  }
  // ---- edge head + log_softmax(4) ----
  f16x2 th[8];
  #pragma unroll
  for (int j=0;j<8;j++){
    float acc0 = eb1L[2*j], acc1 = eb1L[2*j+1];
    #pragma unroll
    for (int kk=0;kk<8;kk++){
      acc0 = dot2(eh4[kk], ew1h[(2*j)*8+kk],   acc0);
      acc1 = dot2(eh4[kk], ew1h[(2*j+1)*8+kk], acc1);
    }
    th[j] = pk2(fmaxf(acc0,0.f), fmaxf(acc1,0.f));
  }
  float y0 = eb2L[0], y1 = eb2L[1], y2 = eb2L[2], y3 = eb2L[3];
  #pragma unroll
  for (int kk=0;kk<8;kk++){
    y0 = dot2(th[kk], ew2h[0*8+kk], y0);
    y1 = dot2(th[kk], ew2h[1*8+kk], y1);
    y2 = dot2(th[kk], ew2h[2*8+kk], y2);
    y3 = dot2(th[kk], ew2h[3*8+kk], y3);
  }
  y0 = fmaxf(y0,0.f); y1 = fmaxf(y1,0.f); y2 = fmaxf(y2,0.f); y3 = fmaxf(y3,0.f);
  float m = fmaxf(fmaxf(y0,y1), fmaxf(y2,y3));
  float l = m + __logf(__expf(y0-m)+__expf(y1-m)+__expf(y2-m)+__expf(y3-m));
  float4 eo; eo.x = y0-l; eo.y = y1-l; eo.z = y2-l; eo.w = y3-l;
  ((float4*)eout)[i] = eo;

  // ---- conv2 alpha -> CSR scatter ----
  float al = hs2[s] + hd2[d];
  #pragma unroll
  for (int kk=0;kk<8;kk++) al = dot2(eh4[kk], w16h[kk], al);
  al = al > 0.f ? al : 0.2f*al;
  float ex = __expf(al);
  int pos = off[d] + atomicAdd(&cnt[d], 1);
  edata[pos] = make_float2(ex, __int_as_float(s));
}

// ---------------- k7: x2 -> node head -> log_softmax(2) --------------------
__global__ __launch_bounds__(256,4) void k7(const float* __restrict__ accb,
    const float* __restrict__ sb, const float* __restrict__ c2b,
    const float* __restrict__ w1p, const float* __restrict__ b1p,
    const float* __restrict__ w2p, const float* __restrict__ b2p,
    float* __restrict__ nout)
{
  __shared__ float wL[256], bL[16], w2L[32], b2L[2], cb[16];
  int tid = threadIdx.x;
  wL[tid] = w1p[tid];
  if (tid < 16){ bL[tid]=b1p[tid]; cb[tid]=c2b[tid]; }
  if (tid < 32) w2L[tid] = w2p[tid];
  if (tid < 2)  b2L[tid] = b2p[tid];
  __syncthreads();
  int n = blockIdx.x*256 + tid;
  if (n >= NN) return;
  float inv = 1.f/(sb[n] + 1e-16f);
  const float* xp = accb + (size_t)n*16;
  float v[16];
  #pragma unroll
  for (int j=0;j<16;j++) v[j] = xp[j]*inv + cb[j];
  float t[16];
  #pragma unroll
  for (int j=0;j<16;j++){
    float acc = bL[j];
    #pragma unroll
    for (int k=0;k<16;k++) acc += v[k]*wL[j*16+k];
    t[j] = fmaxf(acc, 0.f);
  }
  float y0 = b2L[0], y1 = b2L[1];
  #pragma unroll
  for (int k=0;k<16;k++){ y0 += t[k]*w2L[k]; y1 += t[k]*w2L[16+k]; }
  y0 = fmaxf(y0, 0.f); y1 = fmaxf(y1, 0.f);
  float m = fmaxf(y0, y1);
  float l = m + __logf(__expf(y0-m) + __expf(y1-m));
  float2 no; no.x = y0-l; no.y = y1-l;
  ((float2*)nout)[n] = no;
}

extern "C" void kernel_launch(void* const* d_in, const int* in_sizes, int n_in,
                              void* d_out, int out_size, void* d_ws, size_t ws_size,
                              hipStream_t stream)
{
  const float* x  = (const float*)d_in[0];
  const int* ei   = (const int*)d_in[1];
  const float* ea = (const float*)d_in[2];
  const float* c1Wx = (const float*)d_in[3];
  const float* c1We = (const float*)d_in[4];
  const float* c1as = (const float*)d_in[5];
  const float* c1ad = (const float*)d_in[6];
  const float* c1ae = (const float*)d_in[7];
  const float* c1b  = (const float*)d_in[8];
  const float* e1w1 = (const float*)d_in[9];
  const float* e1b1 = (const float*)d_in[10];
  const float* e1w2 = (const float*)d_in[11];
  const float* e1b2 = (const float*)d_in[12];
  const float* e1w3 = (const float*)d_in[13];
  const float* e1b3 = (const float*)d_in[14];
  const float* e1w4 = (const float*)d_in[15];
  const float* e1b4 = (const float*)d_in[16];
  const float* c2Wx = (const float*)d_in[17];
  const float* c2We = (const float*)d_in[18];
  const float* c2as = (const float*)d_in[19];
  const float* c2ad = (const float*)d_in[20];
  const float* c2ae = (const float*)d_in[21];
  const float* c2b  = (const float*)d_in[22];
  const float* nlw1 = (const float*)d_in[23];
  const float* nlb1 = (const float*)d_in[24];
  const float* nlw2 = (const float*)d_in[25];
  const float* nlb2 = (const float*)d_in[26];
  const float* elw1 = (const float*)d_in[27];
  const float* elb1 = (const float*)d_in[28];
  const float* elw2 = (const float*)d_in[29];
  const float* elb2 = (const float*)d_in[30];

  float* ws = (float*)d_ws;
  const size_t N = NN;
  int* off   = (int*)ws;                     // N+1 (pad to N+8)
  int* cnt   = (int*)ws + (N + 8);           // N
  int* bsum  = (int*)ws + (2*N + 8);         // 128
  int* boff  = (int*)ws + (2*N + 136);       // 128
  float* h   = ws + 2*N + 264;               // 16N (h1, then h2)
  float* hs  = h  + 16*N;                    // N  (hs1, then hs2)
  float* hd  = hs + N;                       // N
  float* acc = hd + N;                       // 16N
  float* s   = acc + 16*N;                   // N
  u32* uh    = (u32*)(s + N);                // 16N u32 (f16x2-packed)
  u32* vh    = uh + 16*N;                    // 16N u32
  float2* edata = (float2*)(vh + 16*N);      // NE float2

  float* nout = (float*)d_out;               // [100000, 2]
  float* eout = (float*)d_out + 200000;      // [3200000, 4]

  const int GE = (NE + 255)/256;
  const int GN = (NN + 255)/256;

  (void)hipMemsetAsync(cnt, 0, N*sizeof(int), stream);
  khist<<<GE, 256, 0, stream>>>(ei, cnt);
  kscanA<<<NB, 1024, 0, stream>>>(cnt, bsum);
  kscanB<<<1, 64, 0, stream>>>(bsum, boff, off + NN);
  kscanC<<<NB, 1024, 0, stream>>>(cnt, boff, off);
  k1<<<GN, 256, 0, stream>>>(x, c1Wx, c1as, c1ad, h, hs, hd);
  k2a<<<GE, 256, 0, stream>>>(ei, ea, c1We, c1ae, hs, hd, off, cnt, edata);
  kagg<<<(NN+15)/16, 256, 0, stream>>>(edata, off, h, acc, s, cnt);   // also re-zeros cnt
  k4<<<GN, 256, 0, stream>>>(acc, s, c1b, c2Wx, c2as, c2ad, e1w1, h, hs, hd, uh, vh);
  k5<<<GE, 256, 0, stream>>>(ei, ea, uh, vh, hs, hd,
      e1w1, e1b1, e1w2, e1b2, e1w3, e1b3, e1w4, e1b4,
      c2We, c2ae, elw1, elb1, elw2, elb2,
      off, cnt, edata, eout);
  kagg<<<(NN+15)/16, 256, 0, stream>>>(edata, off, h, acc, s, cnt);
  k7<<<GN, 256, 0, stream>>>(acc, s, c2b, nlw1, nlb1, nlw2, nlb2, nout);
}

// Round 12
// 858.234 us; speedup vs baseline: 9.8409x; 1.1503x over previous
//
#include <hip/hip_runtime.h>

#define NN 100000
#define NE 3200000
#define NB 98   // ceil(NN/1024)

typedef unsigned int u32;
typedef _Float16 f16x2 __attribute__((ext_vector_type(2)));
typedef __fp16 fp16v2 __attribute__((ext_vector_type(2)));

__device__ __forceinline__ int clampi(int s){
  s = s < 0 ? 0 : s;
  return s >= NN ? NN-1 : s;
}

__device__ __forceinline__ f16x2 pk2(float x, float y){
  fp16v2 r = __builtin_amdgcn_cvt_pkrtz(x, y);
  return __builtin_bit_cast(f16x2, r);
}
__device__ __forceinline__ float dot2(f16x2 a, f16x2 b, float c){
  return __builtin_amdgcn_fdot2(a, b, c, false);
}
__device__ __forceinline__ float f16lo(u32 w){
  __fp16 h = __builtin_bit_cast(__fp16, (unsigned short)(w & 0xffffu));
  return (float)h;
}
__device__ __forceinline__ float f16hi(u32 w){
  __fp16 h = __builtin_bit_cast(__fp16, (unsigned short)(w >> 16));
  return (float)h;
}

// dual-accumulator dot (f32, used by k4)
template<int N4>
__device__ __forceinline__ float dotl(const float* __restrict__ a, const float* w){
  float acc0 = 0.f, acc1 = 0.f;
  #pragma unroll
  for (int k = 0; k < N4; k += 2){
    float4 q0 = ((const float4*)w)[k];
    acc0 += a[4*k]*q0.x + a[4*k+1]*q0.y + a[4*k+2]*q0.z + a[4*k+3]*q0.w;
    float4 q1 = ((const float4*)w)[k+1];
    acc1 += a[4*k+4]*q1.x + a[4*k+5]*q1.y + a[4*k+6]*q1.z + a[4*k+7]*q1.w;
  }
  return acc0 + acc1;
}

// ---------------- khist: cnt[d]++ ------------------------------------------
__global__ __launch_bounds__(256,8) void khist(const int* __restrict__ ei, int* __restrict__ cnt){
  int i = blockIdx.x*256 + threadIdx.x;
  if (i >= NE) return;
  atomicAdd(&cnt[clampi(ei[NE+i])], 1);
}

// ---------------- kscanA: per-block sums of cnt -----------------------------
__global__ __launch_bounds__(1024) void kscanA(const int* __restrict__ cnt, int* __restrict__ bsum){
  __shared__ int wsum[16];
  int tid = threadIdx.x;
  int i = blockIdx.x*1024 + tid;
  int x = (i < NN) ? cnt[i] : 0;
  #pragma unroll
  for (int ofs = 1; ofs < 64; ofs <<= 1) x += __shfl_xor(x, ofs, 64);
  if ((tid & 63) == 0) wsum[tid >> 6] = x;
  __syncthreads();
  if (tid == 0){
    int t = 0;
    #pragma unroll
    for (int k = 0; k < 16; k++) t += wsum[k];
    bsum[blockIdx.x] = t;
  }
}

// ---------------- kscanB: scan the 98 block sums ----------------------------
__global__ void kscanB(const int* __restrict__ bsum, int* __restrict__ boff, int* __restrict__ offN){
  if (threadIdx.x == 0){
    int c = 0;
    for (int b = 0; b < NB; b++){ boff[b] = c; c += bsum[b]; }
    offN[0] = c;
  }
}

// ---------------- kscanC: block-local scan + offset; cnt = 0 ----------------
__global__ __launch_bounds__(1024) void kscanC(int* __restrict__ cnt, const int* __restrict__ boff,
                                               int* __restrict__ off){
  __shared__ int wsum[16];
  int tid = threadIdx.x;
  int i = blockIdx.x*1024 + tid;
  int v = (i < NN) ? cnt[i] : 0;
  int x = v;
  #pragma unroll
  for (int ofs = 1; ofs < 64; ofs <<= 1){
    int t = __shfl_up(x, ofs, 64);
    if ((tid & 63) >= ofs) x += t;
  }
  if ((tid & 63) == 63) wsum[tid >> 6] = x;
  __syncthreads();
  if (tid < 16){
    int y = wsum[tid];
    #pragma unroll
    for (int ofs = 1; ofs < 16; ofs <<= 1){
      int t = __shfl_up(y, ofs, 64);
      if (tid >= ofs) y += t;
    }
    wsum[tid] = y;
  }
  __syncthreads();
  int wb = (tid >= 64) ? wsum[(tid >> 6) - 1] : 0;
  if (i < NN){ off[i] = boff[blockIdx.x] + wb + x - v; cnt[i] = 0; }
}

// ---------------- k1: h1 = x @ c1_Wx^T ; hs1 ; hd1 --------------------------
__global__ __launch_bounds__(256,4) void k1(const float* __restrict__ x,
    const float* __restrict__ Wx, const float* __restrict__ asrc, const float* __restrict__ adst,
    float* __restrict__ h1, float* __restrict__ hs1, float* __restrict__ hd1)
{
  __shared__ float wL[64], aS[16], aD[16];
  int tid = threadIdx.x;
  if (tid < 64) wL[tid] = Wx[tid];
  if (tid < 16){ aS[tid] = asrc[tid]; aD[tid] = adst[tid]; }
  __syncthreads();
  int n = blockIdx.x*256 + tid;
  if (n >= NN) return;
  float4 xr = ((const float4*)x)[n];
  float hs=0.f, hd=0.f;
  float* hrow = h1 + (size_t)n*16;
  #pragma unroll
  for (int j=0;j<16;j++){
    float h = xr.x*wL[j*4+0] + xr.y*wL[j*4+1] + xr.z*wL[j*4+2] + xr.w*wL[j*4+3];
    hrow[j] = h; hs += h*aS[j]; hd += h*aD[j];
  }
  hs1[n]=hs; hd1[n]=hd;
}

// ---------------- k2a: alpha1 -> scatter (ex, src) into CSR slot ------------
__global__ __launch_bounds__(256,8) void k2a(const int* __restrict__ ei,
    const float* __restrict__ ea, const float* __restrict__ We, const float* __restrict__ aedge,
    const float* __restrict__ hs1, const float* __restrict__ hd1,
    const int* __restrict__ off, int* __restrict__ cnt, float2* __restrict__ edata)
{
  __shared__ float w6[6];
  int tid = threadIdx.x;
  if (tid < 6){
    float acc = 0.f;
    for (int j=0;j<16;j++) acc += aedge[j] * We[j*6+tid];
    w6[tid] = acc;
  }
  __syncthreads();
  int i = blockIdx.x*256 + tid;
  if (i >= NE) return;
  int s = clampi(ei[i]);
  int d = clampi(ei[NE + i]);
  const float2* eap = (const float2*)ea + (size_t)i*3;
  float2 u0 = eap[0], u1 = eap[1], u2 = eap[2];
  float al = hs1[s] + hd1[d]
    + u0.x*w6[0] + u0.y*w6[1] + u1.x*w6[2]
    + u1.y*w6[3] + u2.x*w6[4] + u2.y*w6[5];
  al = al > 0.f ? al : 0.2f*al;
  float ex = __expf(al);
  int pos = off[d] + atomicAdd(&cnt[d], 1);
  edata[pos] = make_float2(ex, __int_as_float(s));
}

// ---------------- kagg: per-node CSR reduce (16 lanes = 16 features) --------
// (256,8): gather-latency kernel, tiny VGPR use -> max waves for latency hiding.
__global__ __launch_bounds__(256,8) void kagg(const float2* __restrict__ edata,
    const int* __restrict__ off, const float* __restrict__ h,
    float* __restrict__ acc, float* __restrict__ s, int* __restrict__ cnt)
{
  int n = (blockIdx.x*256 + threadIdx.x) >> 4;
  int j = threadIdx.x & 15;
  if (n >= NN) return;
  int beg = off[n], end = off[n+1];
  float aj = 0.f, sl = 0.f;
  for (int k = beg; k < end; ++k){
    float2 p = edata[k];
    int src = __float_as_int(p.y);
    aj += p.x * h[(size_t)src*16 + j];
    sl += p.x;
  }
  acc[(size_t)n*16 + j] = aj;
  if (j == 0){ s[n] = sl; cnt[n] = 0; }
}

// ---------------- k4: x1 = acc/s + b1 ; h2 ; hs2 ; hd2 ; u,v packed f16 -----
__global__ __launch_bounds__(256,2) void k4(const float* __restrict__ accb,
    const float* __restrict__ sb, const float* __restrict__ c1b, const float* __restrict__ Wx2,
    const float* __restrict__ a2s, const float* __restrict__ a2d,
    const float* __restrict__ w1p,
    float* __restrict__ h2,
    float* __restrict__ hs2, float* __restrict__ hd2,
    u32* __restrict__ uh, u32* __restrict__ vh)
{
  __shared__ float wL[256], bL[16], aS[16], aD[16];
  __shared__ float w1sL[32*16], w1dL[32*16];
  int tid = threadIdx.x;
  wL[tid] = Wx2[tid];
  if (tid < 16){ bL[tid]=c1b[tid]; aS[tid]=a2s[tid]; aD[tid]=a2d[tid]; }
  for (int idx=tid; idx<512; idx+=256){
    int j=idx>>4, k=idx&15;
    w1sL[idx] = w1p[j*38+k];
    w1dL[idx] = w1p[j*38+22+k];
  }
  __syncthreads();
  int n = blockIdx.x*256 + tid;
  if (n >= NN) return;
  float inv = 1.f/(sb[n] + 1e-16f);
  float xv[16];
  const float* xp = accb + (size_t)n*16;
  #pragma unroll
  for (int j=0;j<16;j++) xv[j] = xp[j]*inv + bL[j];
  float hs=0.f, hd=0.f;
  float* h2r = h2 + (size_t)n*16;
  #pragma unroll
  for (int j=0;j<16;j++){
    float acc = 0.f;
    #pragma unroll
    for (int k=0;k<16;k++) acc += xv[k]*wL[j*16+k];
    h2r[j] = acc; hs += acc*aS[j]; hd += acc*aD[j];
  }
  hs2[n]=hs; hd2[n]=hd;
  u32* ur = uh + (size_t)n*16;
  u32* vr = vh + (size_t)n*16;
  #pragma unroll
  for (int j=0;j<16;j++){
    float u0 = dotl<4>(xv, &w1sL[(2*j)*16]);
    float u1 = dotl<4>(xv, &w1sL[(2*j+1)*16]);
    ur[j] = __builtin_bit_cast(u32, pk2(u0, u1));
    float v0 = dotl<4>(xv, &w1dL[(2*j)*16]);
    float v1 = dotl<4>(xv, &w1dL[(2*j+1)*16]);
    vr[j] = __builtin_bit_cast(u32, pk2(v0, v1));
  }
}

// ---------------- k5: edge MLP (f16 dot2) + edge head + alpha2 scatter ------
// (256,6): r11 showed VGPR=52 at a (256,3) cap (occupancy 43%, VALU 55%, HBM 34%
// -> latency-bound with self-imposed wave starvation). Budget 512/6=85 >= 52.
__global__ __launch_bounds__(256,6) void k5(
    const int* __restrict__ ei, const float* __restrict__ ea,
    const u32* __restrict__ uh, const u32* __restrict__ vh,
    const float* __restrict__ hs2, const float* __restrict__ hd2,
    const float* w1p, const float* b1p, const float* w2p, const float* b2p,
    const float* w3p, const float* b3p, const float* w4p, const float* b4p,
    const float* We2, const float* a2e,
    const float* ew1p, const float* eb1p, const float* ew2p, const float* eb2p,
    const int* __restrict__ off, int* __restrict__ cnt, float2* __restrict__ edata,
    float* __restrict__ eout)
{
  __shared__ __align__(16) f16x2 w1eh[32*4];  __shared__ float b1L[32];
  __shared__ __align__(16) f16x2 w2h[64*16];  __shared__ float b2L[64];
  __shared__ __align__(16) f16x2 w3h[32*32];  __shared__ float b3L[32];
  __shared__ __align__(16) f16x2 w4h[16*16];  __shared__ float b4L[16];
  __shared__ __align__(16) f16x2 ew1h[16*8];  __shared__ float eb1L[16];
  __shared__ __align__(16) f16x2 ew2h[4*8];   __shared__ float eb2L[4];
  __shared__ __align__(16) f16x2 w16h[8];
  int tid = threadIdx.x;
  if (tid < 128){
    int j=tid>>2, kk=tid&3;
    int k0=2*kk, k1=2*kk+1;
    float v0 = (k0<6) ? w1p[j*38+16+k0] : 0.f;
    float v1 = (k1<6) ? w1p[j*38+16+k1] : 0.f;
    w1eh[tid] = pk2(v0, v1);
  }
  for (int idx=tid; idx<1024; idx+=256){
    int j=idx>>4, kk=idx&15;
    w2h[idx] = pk2(w2p[j*32+2*kk], w2p[j*32+2*kk+1]);
  }
  for (int idx=tid; idx<1024; idx+=256){
    int j=idx>>5, kk=idx&31;
    w3h[idx] = pk2(w3p[j*64+2*kk], w3p[j*64+2*kk+1]);
  }
  if (tid < 256){
    int j=tid>>4, kk=tid&15;
    w4h[tid] = pk2(w4p[j*32+2*kk], w4p[j*32+2*kk+1]);
  }
  if (tid < 128){
    int j=tid>>3, kk=tid&7;
    ew1h[tid] = pk2(ew1p[j*16+2*kk], ew1p[j*16+2*kk+1]);
  }
  if (tid < 32){
    int j=tid>>3, kk=tid&7;
    ew2h[tid] = pk2(ew2p[j*16+2*kk], ew2p[j*16+2*kk+1]);
  }
  if (tid < 8){
    float s0=0.f, s1=0.f;
    for (int j=0;j<16;j++){
      s0 += a2e[j] * We2[j*16 + 2*tid];
      s1 += a2e[j] * We2[j*16 + 2*tid + 1];
    }
    w16h[tid] = pk2(s0, s1);
  }
  if (tid < 64) b2L[tid] = b2p[tid];
  if (tid < 32){ b1L[tid] = b1p[tid]; b3L[tid] = b3p[tid]; }
  if (tid < 16){ b4L[tid] = b4p[tid]; eb1L[tid] = eb1p[tid]; }
  if (tid < 4)  eb2L[tid] = eb2p[tid];
  __syncthreads();

  int i = blockIdx.x*256 + tid;
  if (i >= NE) return;
  int s = clampi(ei[i]);
  int d = clampi(ei[NE + i]);

  // ---- layer 1: a1 = relu(u[s] + v[d] + W1e.ea + b1) ----
  f16x2 a1h[16];
  {
    const float2* eap = (const float2*)ea + (size_t)i*3;
    float2 e0=eap[0], e1=eap[1], e2=eap[2];
    f16x2 eh[4];
    eh[0]=pk2(e0.x,e0.y); eh[1]=pk2(e1.x,e1.y); eh[2]=pk2(e2.x,e2.y); eh[3]=pk2(0.f,0.f);
    const uint4* up = (const uint4*)(uh + (size_t)s*16);
    const uint4* vp = (const uint4*)(vh + (size_t)d*16);
    uint4 U[4], V[4];
    #pragma unroll
    for (int q=0;q<4;q++){ U[q]=up[q]; V[q]=vp[q]; }
    u32 uw[16], vw[16];
    #pragma unroll
    for (int q=0;q<4;q++){
      uw[4*q]=U[q].x; uw[4*q+1]=U[q].y; uw[4*q+2]=U[q].z; uw[4*q+3]=U[q].w;
      vw[4*q]=V[q].x; vw[4*q+1]=V[q].y; vw[4*q+2]=V[q].z; vw[4*q+3]=V[q].w;
    }
    #pragma unroll
    for (int j=0;j<16;j++){
      float t0 = b1L[2*j]   + f16lo(uw[j]) + f16lo(vw[j]);
      float t1 = b1L[2*j+1] + f16hi(uw[j]) + f16hi(vw[j]);
      #pragma unroll
      for (int kk=0;kk<4;kk++){
        t0 = dot2(eh[kk], w1eh[(2*j)*4+kk],   t0);
        t1 = dot2(eh[kk], w1eh[(2*j+1)*4+kk], t1);
      }
      a1h[j] = pk2(fmaxf(t0,0.f), fmaxf(t1,0.f));
    }
  }
  // ---- layer 2: 32 -> 64 ----
  f16x2 a2h[32];
  #pragma unroll
  for (int j=0;j<32;j++){
    float acc0 = b2L[2*j], acc1 = b2L[2*j+1];
    #pragma unroll
    for (int kk=0;kk<16;kk++){
      acc0 = dot2(a1h[kk], w2h[(2*j)*16+kk],   acc0);
      acc1 = dot2(a1h[kk], w2h[(2*j+1)*16+kk], acc1);
    }
    a2h[j] = pk2(fmaxf(acc0,0.f), fmaxf(acc1,0.f));
  }
  // ---- layer 3: 64 -> 32 ----
  f16x2 a3h[16];
  #pragma unroll
  for (int j=0;j<16;j++){
    float acc0 = b3L[2*j], acc1 = b3L[2*j+1];
    #pragma unroll
    for (int kk=0;kk<32;kk++){
      acc0 = dot2(a2h[kk], w3h[(2*j)*32+kk],   acc0);
      acc1 = dot2(a2h[kk], w3h[(2*j+1)*32+kk], acc1);
    }
    a3h[j] = pk2(fmaxf(acc0,0.f), fmaxf(acc1,0.f));
  }
  // ---- layer 4: 32 -> 16 (no relu) ----
  f16x2 eh4[8];
  #pragma unroll
  for (int j=0;j<8;j++){
    float acc0 = b4L[2*j], acc1 = b4L[2*j+1];
    #pragma unroll
    for (int kk=0;kk<16;kk++){
      acc0 = dot2(a3h[kk], w4h[(2*j)*16+kk],   acc0);
      acc1 = dot2(a3h[kk], w4h[(2*j+1)*16+kk], acc1);
    }
    eh4[j] = pk2(acc0, acc1);
  }
  // ---- edge head + log_softmax(4) ----
  f16x2 th[8];
  #pragma unroll
  for (int j=0;j<8;j++){
    float acc0 = eb1L[2*j], acc1 = eb1L[2*j+1];
    #pragma unroll
    for (int kk=0;kk<8;kk++){
      acc0 = dot2(eh4[kk], ew1h[(2*j)*8+kk],   acc0);
      acc1 = dot2(eh4[kk], ew1h[(2*j+1)*8+kk], acc1);
    }
    th[j] = pk2(fmaxf(acc0,0.f), fmaxf(acc1,0.f));
  }
  float y0 = eb2L[0], y1 = eb2L[1], y2 = eb2L[2], y3 = eb2L[3];
  #pragma unroll
  for (int kk=0;kk<8;kk++){
    y0 = dot2(th[kk], ew2h[0*8+kk], y0);
    y1 = dot2(th[kk], ew2h[1*8+kk], y1);
    y2 = dot2(th[kk], ew2h[2*8+kk], y2);
    y3 = dot2(th[kk], ew2h[3*8+kk], y3);
  }
  y0 = fmaxf(y0,0.f); y1 = fmaxf(y1,0.f); y2 = fmaxf(y2,0.f); y3 = fmaxf(y3,0.f);
  float m = fmaxf(fmaxf(y0,y1), fmaxf(y2,y3));
  float l = m + __logf(__expf(y0-m)+__expf(y1-m)+__expf(y2-m)+__expf(y3-m));
  float4 eo; eo.x = y0-l; eo.y = y1-l; eo.z = y2-l; eo.w = y3-l;
  ((float4*)eout)[i] = eo;

  // ---- conv2 alpha -> CSR scatter ----
  float al = hs2[s] + hd2[d];
  #pragma unroll
  for (int kk=0;kk<8;kk++) al = dot2(eh4[kk], w16h[kk], al);
  al = al > 0.f ? al : 0.2f*al;
  float ex = __expf(al);
  int pos = off[d] + atomicAdd(&cnt[d], 1);
  edata[pos] = make_float2(ex, __int_as_float(s));
}

// ---------------- k7: x2 -> node head -> log_softmax(2) --------------------
__global__ __launch_bounds__(256,4) void k7(const float* __restrict__ accb,
    const float* __restrict__ sb, const float* __restrict__ c2b,
    const float* __restrict__ w1p, const float* __restrict__ b1p,
    const float* __restrict__ w2p, const float* __restrict__ b2p,
    float* __restrict__ nout)
{
  __shared__ float wL[256], bL[16], w2L[32], b2L[2], cb[16];
  int tid = threadIdx.x;
  wL[tid] = w1p[tid];
  if (tid < 16){ bL[tid]=b1p[tid]; cb[tid]=c2b[tid]; }
  if (tid < 32) w2L[tid] = w2p[tid];
  if (tid < 2)  b2L[tid] = b2p[tid];
  __syncthreads();
  int n = blockIdx.x*256 + tid;
  if (n >= NN) return;
  float inv = 1.f/(sb[n] + 1e-16f);
  const float* xp = accb + (size_t)n*16;
  float v[16];
  #pragma unroll
  for (int j=0;j<16;j++) v[j] = xp[j]*inv + cb[j];
  float t[16];
  #pragma unroll
  for (int j=0;j<16;j++){
    float acc = bL[j];
    #pragma unroll
    for (int k=0;k<16;k++) acc += v[k]*wL[j*16+k];
    t[j] = fmaxf(acc, 0.f);
  }
  float y0 = b2L[0], y1 = b2L[1];
  #pragma unroll
  for (int k=0;k<16;k++){ y0 += t[k]*w2L[k]; y1 += t[k]*w2L[16+k]; }
  y0 = fmaxf(y0, 0.f); y1 = fmaxf(y1, 0.f);
  float m = fmaxf(y0, y1);
  float l = m + __logf(__expf(y0-m) + __expf(y1-m));
  float2 no; no.x = y0-l; no.y = y1-l;
  ((float2*)nout)[n] = no;
}

extern "C" void kernel_launch(void* const* d_in, const int* in_sizes, int n_in,
                              void* d_out, int out_size, void* d_ws, size_t ws_size,
                              hipStream_t stream)
{
  const float* x  = (const float*)d_in[0];
  const int* ei   = (const int*)d_in[1];
  const float* ea = (const float*)d_in[2];
  const float* c1Wx = (const float*)d_in[3];
  const float* c1We = (const float*)d_in[4];
  const float* c1as = (const float*)d_in[5];
  const float* c1ad = (const float*)d_in[6];
  const float* c1ae = (const float*)d_in[7];
  const float* c1b  = (const float*)d_in[8];
  const float* e1w1 = (const float*)d_in[9];
  const float* e1b1 = (const float*)d_in[10];
  const float* e1w2 = (const float*)d_in[11];
  const float* e1b2 = (const float*)d_in[12];
  const float* e1w3 = (const float*)d_in[13];
  const float* e1b3 = (const float*)d_in[14];
  const float* e1w4 = (const float*)d_in[15];
  const float* e1b4 = (const float*)d_in[16];
  const float* c2Wx = (const float*)d_in[17];
  const float* c2We = (const float*)d_in[18];
  const float* c2as = (const float*)d_in[19];
  const float* c2ad = (const float*)d_in[20];
  const float* c2ae = (const float*)d_in[21];
  const float* c2b  = (const float*)d_in[22];
  const float* nlw1 = (const float*)d_in[23];
  const float* nlb1 = (const float*)d_in[24];
  const float* nlw2 = (const float*)d_in[25];
  const float* nlb2 = (const float*)d_in[26];
  const float* elw1 = (const float*)d_in[27];
  const float* elb1 = (const float*)d_in[28];
  const float* elw2 = (const float*)d_in[29];
  const float* elb2 = (const float*)d_in[30];

  float* ws = (float*)d_ws;
  const size_t N = NN;
  int* off   = (int*)ws;                     // N+1 (pad to N+8)
  int* cnt   = (int*)ws + (N + 8);           // N
  int* bsum  = (int*)ws + (2*N + 8);         // 128
  int* boff  = (int*)ws + (2*N + 136);       // 128
  float* h   = ws + 2*N + 264;               // 16N (h1, then h2)
  float* hs  = h  + 16*N;                    // N  (hs1, then hs2)
  float* hd  = hs + N;                       // N
  float* acc = hd + N;                       // 16N
  float* s   = acc + 16*N;                   // N
  u32* uh    = (u32*)(s + N);                // 16N u32 (f16x2-packed)
  u32* vh    = uh + 16*N;                    // 16N u32
  float2* edata = (float2*)(vh + 16*N);      // NE float2

  float* nout = (float*)d_out;               // [100000, 2]
  float* eout = (float*)d_out + 200000;      // [3200000, 4]

  const int GE = (NE + 255)/256;
  const int GN = (NN + 255)/256;

  (void)hipMemsetAsync(cnt, 0, N*sizeof(int), stream);
  khist<<<GE, 256, 0, stream>>>(ei, cnt);
  kscanA<<<NB, 1024, 0, stream>>>(cnt, bsum);
  kscanB<<<1, 64, 0, stream>>>(bsum, boff, off + NN);
  kscanC<<<NB, 1024, 0, stream>>>(cnt, boff, off);
  k1<<<GN, 256, 0, stream>>>(x, c1Wx, c1as, c1ad, h, hs, hd);
  k2a<<<GE, 256, 0, stream>>>(ei, ea, c1We, c1ae, hs, hd, off, cnt, edata);
  kagg<<<(NN+15)/16, 256, 0, stream>>>(edata, off, h, acc, s, cnt);   // also re-zeros cnt
  k4<<<GN, 256, 0, stream>>>(acc, s, c1b, c2Wx, c2as, c2ad, e1w1, h, hs, hd, uh, vh);
  k5<<<GE, 256, 0, stream>>>(ei, ea, uh, vh, hs, hd,
      e1w1, e1b1, e1w2, e1b2, e1w3, e1b3, e1w4, e1b4,
      c2We, c2ae, elw1, elb1, elw2, elb2,
      off, cnt, edata, eout);
  kagg<<<(NN+15)/16, 256, 0, stream>>>(edata, off, h, acc, s, cnt);
  k7<<<GN, 256, 0, stream>>>(acc, s, c2b, nlw1, nlb1, nlw2, nlb2, nout);
}

// Round 13
// 803.633 us; speedup vs baseline: 10.5095x; 1.0679x over previous
//
#include <hip/hip_runtime.h>

#define NN 100000
#define NE 3200000
#define NB 98   // ceil(NN/1024)

typedef unsigned int u32;
typedef unsigned short u16;
typedef _Float16 f16x2 __attribute__((ext_vector_type(2)));
typedef __fp16 fp16v2 __attribute__((ext_vector_type(2)));

__device__ __forceinline__ int clampi(int s){
  s = s < 0 ? 0 : s;
  return s >= NN ? NN-1 : s;
}

__device__ __forceinline__ f16x2 pk2(float x, float y){
  fp16v2 r = __builtin_amdgcn_cvt_pkrtz(x, y);
  return __builtin_bit_cast(f16x2, r);
}
__device__ __forceinline__ float dot2(f16x2 a, f16x2 b, float c){
  return __builtin_amdgcn_fdot2(a, b, c, false);
}
__device__ __forceinline__ float f16lo(u32 w){
  __fp16 h = __builtin_bit_cast(__fp16, (u16)(w & 0xffffu));
  return (float)h;
}
__device__ __forceinline__ float f16hi(u32 w){
  __fp16 h = __builtin_bit_cast(__fp16, (u16)(w >> 16));
  return (float)h;
}
__device__ __forceinline__ float f16u(u16 w){
  __fp16 h = __builtin_bit_cast(__fp16, w);
  return (float)h;
}

// dual-accumulator dot (f32, used by k4)
template<int N4>
__device__ __forceinline__ float dotl(const float* __restrict__ a, const float* w){
  float acc0 = 0.f, acc1 = 0.f;
  #pragma unroll
  for (int k = 0; k < N4; k += 2){
    float4 q0 = ((const float4*)w)[k];
    acc0 += a[4*k]*q0.x + a[4*k+1]*q0.y + a[4*k+2]*q0.z + a[4*k+3]*q0.w;
    float4 q1 = ((const float4*)w)[k+1];
    acc1 += a[4*k+4]*q1.x + a[4*k+5]*q1.y + a[4*k+6]*q1.z + a[4*k+7]*q1.w;
  }
  return acc0 + acc1;
}

// ---------------- khist: cnt[d]++ ------------------------------------------
__global__ __launch_bounds__(256,8) void khist(const int* __restrict__ ei, int* __restrict__ cnt){
  int i = blockIdx.x*256 + threadIdx.x;
  if (i >= NE) return;
  atomicAdd(&cnt[clampi(ei[NE+i])], 1);
}

// ---------------- kscanA: per-block sums of cnt -----------------------------
__global__ __launch_bounds__(1024) void kscanA(const int* __restrict__ cnt, int* __restrict__ bsum){
  __shared__ int wsum[16];
  int tid = threadIdx.x;
  int i = blockIdx.x*1024 + tid;
  int x = (i < NN) ? cnt[i] : 0;
  #pragma unroll
  for (int ofs = 1; ofs < 64; ofs <<= 1) x += __shfl_xor(x, ofs, 64);
  if ((tid & 63) == 0) wsum[tid >> 6] = x;
  __syncthreads();
  if (tid == 0){
    int t = 0;
    #pragma unroll
    for (int k = 0; k < 16; k++) t += wsum[k];
    bsum[blockIdx.x] = t;
  }
}

// ---------------- kscanB: scan the 98 block sums ----------------------------
__global__ void kscanB(const int* __restrict__ bsum, int* __restrict__ boff, int* __restrict__ offN){
  if (threadIdx.x == 0){
    int c = 0;
    for (int b = 0; b < NB; b++){ boff[b] = c; c += bsum[b]; }
    offN[0] = c;
  }
}

// ---------------- kscanC: block-local scan + offset; cnt = 0 ----------------
__global__ __launch_bounds__(1024) void kscanC(int* __restrict__ cnt, const int* __restrict__ boff,
                                               int* __restrict__ off){
  __shared__ int wsum[16];
  int tid = threadIdx.x;
  int i = blockIdx.x*1024 + tid;
  int v = (i < NN) ? cnt[i] : 0;
  int x = v;
  #pragma unroll
  for (int ofs = 1; ofs < 64; ofs <<= 1){
    int t = __shfl_up(x, ofs, 64);
    if ((tid & 63) >= ofs) x += t;
  }
  if ((tid & 63) == 63) wsum[tid >> 6] = x;
  __syncthreads();
  if (tid < 16){
    int y = wsum[tid];
    #pragma unroll
    for (int ofs = 1; ofs < 16; ofs <<= 1){
      int t = __shfl_up(y, ofs, 64);
      if (tid >= ofs) y += t;
    }
    wsum[tid] = y;
  }
  __syncthreads();
  int wb = (tid >= 64) ? wsum[(tid >> 6) - 1] : 0;
  if (i < NN){ off[i] = boff[blockIdx.x] + wb + x - v; cnt[i] = 0; }
}

// ---------------- k1: h1 (f16-packed) = x @ c1_Wx^T ; hs1 ; hd1 -------------
__global__ __launch_bounds__(256,4) void k1(const float* __restrict__ x,
    const float* __restrict__ Wx, const float* __restrict__ asrc, const float* __restrict__ adst,
    u32* __restrict__ hpk, float* __restrict__ hs1, float* __restrict__ hd1)
{
  __shared__ float wL[64], aS[16], aD[16];
  int tid = threadIdx.x;
  if (tid < 64) wL[tid] = Wx[tid];
  if (tid < 16){ aS[tid] = asrc[tid]; aD[tid] = adst[tid]; }
  __syncthreads();
  int n = blockIdx.x*256 + tid;
  if (n >= NN) return;
  float4 xr = ((const float4*)x)[n];
  float hs=0.f, hd=0.f;
  float hv[16];
  #pragma unroll
  for (int j=0;j<16;j++){
    float h = xr.x*wL[j*4+0] + xr.y*wL[j*4+1] + xr.z*wL[j*4+2] + xr.w*wL[j*4+3];
    hv[j] = h; hs += h*aS[j]; hd += h*aD[j];
  }
  u32* hr = hpk + (size_t)n*8;
  #pragma unroll
  for (int j=0;j<8;j++) hr[j] = __builtin_bit_cast(u32, pk2(hv[2*j], hv[2*j+1]));
  hs1[n]=hs; hd1[n]=hd;
}

// ---------------- k2a: alpha1 -> scatter (ex, src) into CSR slot ------------
__global__ __launch_bounds__(256,8) void k2a(const int* __restrict__ ei,
    const float* __restrict__ ea, const float* __restrict__ We, const float* __restrict__ aedge,
    const float* __restrict__ hs1, const float* __restrict__ hd1,
    const int* __restrict__ off, int* __restrict__ cnt, float2* __restrict__ edata)
{
  __shared__ float w6[6];
  int tid = threadIdx.x;
  if (tid < 6){
    float acc = 0.f;
    for (int j=0;j<16;j++) acc += aedge[j] * We[j*6+tid];
    w6[tid] = acc;
  }
  __syncthreads();
  int i = blockIdx.x*256 + tid;
  if (i >= NE) return;
  int s = clampi(ei[i]);
  int d = clampi(ei[NE + i]);
  const float2* eap = (const float2*)ea + (size_t)i*3;
  float2 u0 = eap[0], u1 = eap[1], u2 = eap[2];
  float al = hs1[s] + hd1[d]
    + u0.x*w6[0] + u0.y*w6[1] + u1.x*w6[2]
    + u1.y*w6[3] + u2.x*w6[4] + u2.y*w6[5];
  al = al > 0.f ? al : 0.2f*al;
  float ex = __expf(al);
  int pos = off[d] + atomicAdd(&cnt[d], 1);
  edata[pos] = make_float2(ex, __int_as_float(s));
}

// ---------------- kagg: per-node CSR reduce, h f16-packed (L2-resident) -----
__global__ __launch_bounds__(256,8) void kagg(const float2* __restrict__ edata,
    const int* __restrict__ off, const u16* __restrict__ hpk,
    float* __restrict__ acc, float* __restrict__ s, int* __restrict__ cnt)
{
  int n = (blockIdx.x*256 + threadIdx.x) >> 4;
  int j = threadIdx.x & 15;
  if (n >= NN) return;
  int beg = off[n], end = off[n+1];
  float aj = 0.f, sl = 0.f;
  for (int k = beg; k < end; ++k){
    float2 p = edata[k];
    int src = __float_as_int(p.y);
    aj += p.x * f16u(hpk[(size_t)src*16 + j]);
    sl += p.x;
  }
  acc[(size_t)n*16 + j] = aj;
  if (j == 0){ s[n] = sl; cnt[n] = 0; }
}

// ---------------- k4: x1 = acc/s + b1 ; h2 (f16-packed) ; hs2 ; hd2 ; u,v ---
__global__ __launch_bounds__(256,2) void k4(const float* __restrict__ accb,
    const float* __restrict__ sb, const float* __restrict__ c1b, const float* __restrict__ Wx2,
    const float* __restrict__ a2s, const float* __restrict__ a2d,
    const float* __restrict__ w1p,
    u32* __restrict__ hpk,
    float* __restrict__ hs2, float* __restrict__ hd2,
    u32* __restrict__ uh, u32* __restrict__ vh)
{
  __shared__ float wL[256], bL[16], aS[16], aD[16];
  __shared__ float w1sL[32*16], w1dL[32*16];
  int tid = threadIdx.x;
  wL[tid] = Wx2[tid];
  if (tid < 16){ bL[tid]=c1b[tid]; aS[tid]=a2s[tid]; aD[tid]=a2d[tid]; }
  for (int idx=tid; idx<512; idx+=256){
    int j=idx>>4, k=idx&15;
    w1sL[idx] = w1p[j*38+k];
    w1dL[idx] = w1p[j*38+22+k];
  }
  __syncthreads();
  int n = blockIdx.x*256 + tid;
  if (n >= NN) return;
  float inv = 1.f/(sb[n] + 1e-16f);
  float xv[16];
  const float* xp = accb + (size_t)n*16;
  #pragma unroll
  for (int j=0;j<16;j++) xv[j] = xp[j]*inv + bL[j];
  float hs=0.f, hd=0.f;
  float hv[16];
  #pragma unroll
  for (int j=0;j<16;j++){
    float acc = 0.f;
    #pragma unroll
    for (int k=0;k<16;k++) acc += xv[k]*wL[j*16+k];
    hv[j] = acc; hs += acc*aS[j]; hd += acc*aD[j];
  }
  u32* hr = hpk + (size_t)n*8;
  #pragma unroll
  for (int j=0;j<8;j++) hr[j] = __builtin_bit_cast(u32, pk2(hv[2*j], hv[2*j+1]));
  hs2[n]=hs; hd2[n]=hd;
  u32* ur = uh + (size_t)n*16;
  u32* vr = vh + (size_t)n*16;
  #pragma unroll
  for (int j=0;j<16;j++){
    float u0 = dotl<4>(xv, &w1sL[(2*j)*16]);
    float u1 = dotl<4>(xv, &w1sL[(2*j+1)*16]);
    ur[j] = __builtin_bit_cast(u32, pk2(u0, u1));
    float v0 = dotl<4>(xv, &w1dL[(2*j)*16]);
    float v1 = dotl<4>(xv, &w1dL[(2*j+1)*16]);
    vr[j] = __builtin_bit_cast(u32, pk2(v0, v1));
  }
}

// ---------------- k5: edge MLP (f16 dot2) + edge head + alpha2 scatter ------
// (256,5): budget 102 >= ~52 needed. r12's (256,6) budget 85 induced a VGPR=40
// allocation with ~125MB scratch spill (WRITE 248->373MB); same occupancy
// regime (62.5% cap vs 63.5% measured) without the spill.
__global__ __launch_bounds__(256,5) void k5(
    const int* __restrict__ ei, const float* __restrict__ ea,
    const u32* __restrict__ uh, const u32* __restrict__ vh,
    const float* __restrict__ hs2, const float* __restrict__ hd2,
    const float* w1p, const float* b1p, const float* w2p, const float* b2p,
    const float* w3p, const float* b3p, const float* w4p, const float* b4p,
    const float* We2, const float* a2e,
    const float* ew1p, const float* eb1p, const float* ew2p, const float* eb2p,
    const int* __restrict__ off, int* __restrict__ cnt, float2* __restrict__ edata,
    float* __restrict__ eout)
{
  __shared__ __align__(16) f16x2 w1eh[32*4];  __shared__ float b1L[32];
  __shared__ __align__(16) f16x2 w2h[64*16];  __shared__ float b2L[64];
  __shared__ __align__(16) f16x2 w3h[32*32];  __shared__ float b3L[32];
  __shared__ __align__(16) f16x2 w4h[16*16];  __shared__ float b4L[16];
  __shared__ __align__(16) f16x2 ew1h[16*8];  __shared__ float eb1L[16];
  __shared__ __align__(16) f16x2 ew2h[4*8];   __shared__ float eb2L[4];
  __shared__ __align__(16) f16x2 w16h[8];
  int tid = threadIdx.x;
  if (tid < 128){
    int j=tid>>2, kk=tid&3;
    int k0=2*kk, k1=2*kk+1;
    float v0 = (k0<6) ? w1p[j*38+16+k0] : 0.f;
    float v1 = (k1<6) ? w1p[j*38+16+k1] : 0.f;
    w1eh[tid] = pk2(v0, v1);
  }
  for (int idx=tid; idx<1024; idx+=256){
    int j=idx>>4, kk=idx&15;
    w2h[idx] = pk2(w2p[j*32+2*kk], w2p[j*32+2*kk+1]);
  }
  for (int idx=tid; idx<1024; idx+=256){
    int j=idx>>5, kk=idx&31;
    w3h[idx] = pk2(w3p[j*64+2*kk], w3p[j*64+2*kk+1]);
  }
  if (tid < 256){
    int j=tid>>4, kk=tid&15;
    w4h[tid] = pk2(w4p[j*32+2*kk], w4p[j*32+2*kk+1]);
  }
  if (tid < 128){
    int j=tid>>3, kk=tid&7;
    ew1h[tid] = pk2(ew1p[j*16+2*kk], ew1p[j*16+2*kk+1]);
  }
  if (tid < 32){
    int j=tid>>3, kk=tid&7;
    ew2h[tid] = pk2(ew2p[j*16+2*kk], ew2p[j*16+2*kk+1]);
  }
  if (tid < 8){
    float s0=0.f, s1=0.f;
    for (int j=0;j<16;j++){
      s0 += a2e[j] * We2[j*16 + 2*tid];
      s1 += a2e[j] * We2[j*16 + 2*tid + 1];
    }
    w16h[tid] = pk2(s0, s1);
  }
  if (tid < 64) b2L[tid] = b2p[tid];
  if (tid < 32){ b1L[tid] = b1p[tid]; b3L[tid] = b3p[tid]; }
  if (tid < 16){ b4L[tid] = b4p[tid]; eb1L[tid] = eb1p[tid]; }
  if (tid < 4)  eb2L[tid] = eb2p[tid];
  __syncthreads();

  int i = blockIdx.x*256 + tid;
  if (i >= NE) return;
  int s = clampi(ei[i]);
  int d = clampi(ei[NE + i]);

  // ---- layer 1: a1 = relu(u[s] + v[d] + W1e.ea + b1) ----
  f16x2 a1h[16];
  {
    const float2* eap = (const float2*)ea + (size_t)i*3;
    float2 e0=eap[0], e1=eap[1], e2=eap[2];
    f16x2 eh[4];
    eh[0]=pk2(e0.x,e0.y); eh[1]=pk2(e1.x,e1.y); eh[2]=pk2(e2.x,e2.y); eh[3]=pk2(0.f,0.f);
    const uint4* up = (const uint4*)(uh + (size_t)s*16);
    const uint4* vp = (const uint4*)(vh + (size_t)d*16);
    uint4 U[4], V[4];
    #pragma unroll
    for (int q=0;q<4;q++){ U[q]=up[q]; V[q]=vp[q]; }
    u32 uw[16], vw[16];
    #pragma unroll
    for (int q=0;q<4;q++){
      uw[4*q]=U[q].x; uw[4*q+1]=U[q].y; uw[4*q+2]=U[q].z; uw[4*q+3]=U[q].w;
      vw[4*q]=V[q].x; vw[4*q+1]=V[q].y; vw[4*q+2]=V[q].z; vw[4*q+3]=V[q].w;
    }
    #pragma unroll
    for (int j=0;j<16;j++){
      float t0 = b1L[2*j]   + f16lo(uw[j]) + f16lo(vw[j]);
      float t1 = b1L[2*j+1] + f16hi(uw[j]) + f16hi(vw[j]);
      #pragma unroll
      for (int kk=0;kk<4;kk++){
        t0 = dot2(eh[kk], w1eh[(2*j)*4+kk],   t0);
        t1 = dot2(eh[kk], w1eh[(2*j+1)*4+kk], t1);
      }
      a1h[j] = pk2(fmaxf(t0,0.f), fmaxf(t1,0.f));
    }
  }
  // ---- layer 2: 32 -> 64 ----
  f16x2 a2h[32];
  #pragma unroll
  for (int j=0;j<32;j++){
    float acc0 = b2L[2*j], acc1 = b2L[2*j+1];
    #pragma unroll
    for (int kk=0;kk<16;kk++){
      acc0 = dot2(a1h[kk], w2h[(2*j)*16+kk],   acc0);
      acc1 = dot2(a1h[kk], w2h[(2*j+1)*16+kk], acc1);
    }
    a2h[j] = pk2(fmaxf(acc0,0.f), fmaxf(acc1,0.f));
  }
  // ---- layer 3: 64 -> 32 ----
  f16x2 a3h[16];
  #pragma unroll
  for (int j=0;j<16;j++){
    float acc0 = b3L[2*j], acc1 = b3L[2*j+1];
    #pragma unroll
    for (int kk=0;kk<32;kk++){
      acc0 = dot2(a2h[kk], w3h[(2*j)*32+kk],   acc0);
      acc1 = dot2(a2h[kk], w3h[(2*j+1)*32+kk], acc1);
    }
    a3h[j] = pk2(fmaxf(acc0,0.f), fmaxf(acc1,0.f));
  }
  // ---- layer 4: 32 -> 16 (no relu) ----
  f16x2 eh4[8];
  #pragma unroll
  for (int j=0;j<8;j++){
    float acc0 = b4L[2*j], acc1 = b4L[2*j+1];
    #pragma unroll
    for (int kk=0;kk<16;kk++){
      acc0 = dot2(a3h[kk], w4h[(2*j)*16+kk],   acc0);
      acc1 = dot2(a3h[kk], w4h[(2*j+1)*16+kk], acc1);
    }
    eh4[j] = pk2(acc0, acc1);
  }
  // ---- edge head + log_softmax(4) ----
  f16x2 th[8];
  #pragma unroll
  for (int j=0;j<8;j++){
    float acc0 = eb1L[2*j], acc1 = eb1L[2*j+1];
    #pragma unroll
    for (int kk=0;kk<8;kk++){
      acc0 = dot2(eh4[kk], ew1h[(2*j)*8+kk],   acc0);
      acc1 = dot2(eh4[kk], ew1h[(2*j+1)*8+kk], acc1);
    }
    th[j] = pk2(fmaxf(acc0,0.f), fmaxf(acc1,0.f));
  }
  float y0 = eb2L[0], y1 = eb2L[1], y2 = eb2L[2], y3 = eb2L[3];
  #pragma unroll
  for (int kk=0;kk<8;kk++){
    y0 = dot2(th[kk], ew2h[0*8+kk], y0);
    y1 = dot2(th[kk], ew2h[1*8+kk], y1);
    y2 = dot2(th[kk], ew2h[2*8+kk], y2);
    y3 = dot2(th[kk], ew2h[3*8+kk], y3);
  }
  y0 = fmaxf(y0,0.f); y1 = fmaxf(y1,0.f); y2 = fmaxf(y2,0.f); y3 = fmaxf(y3,0.f);
  float m = fmaxf(fmaxf(y0,y1), fmaxf(y2,y3));
  float l = m + __logf(__expf(y0-m)+__expf(y1-m)+__expf(y2-m)+__expf(y3-m));
  float4 eo; eo.x = y0-l; eo.y = y1-l; eo.z = y2-l; eo.w = y3-l;
  ((float4*)eout)[i] = eo;

  // ---- conv2 alpha -> CSR scatter ----
  float al = hs2[s] + hd2[d];
  #pragma unroll
  for (int kk=0;kk<8;kk++) al = dot2(eh4[kk], w16h[kk], al);
  al = al > 0.f ? al : 0.2f*al;
  float ex = __expf(al);
  int pos = off[d] + atomicAdd(&cnt[d], 1);
  edata[pos] = make_float2(ex, __int_as_float(s));
}

// ---------------- k7: x2 -> node head -> log_softmax(2) --------------------
__global__ __launch_bounds__(256,4) void k7(const float* __restrict__ accb,
    const float* __restrict__ sb, const float* __restrict__ c2b,
    const float* __restrict__ w1p, const float* __restrict__ b1p,
    const float* __restrict__ w2p, const float* __restrict__ b2p,
    float* __restrict__ nout)
{
  __shared__ float wL[256], bL[16], w2L[32], b2L[2], cb[16];
  int tid = threadIdx.x;
  wL[tid] = w1p[tid];
  if (tid < 16){ bL[tid]=b1p[tid]; cb[tid]=c2b[tid]; }
  if (tid < 32) w2L[tid] = w2p[tid];
  if (tid < 2)  b2L[tid] = b2p[tid];
  __syncthreads();
  int n = blockIdx.x*256 + tid;
  if (n >= NN) return;
  float inv = 1.f/(sb[n] + 1e-16f);
  const float* xp = accb + (size_t)n*16;
  float v[16];
  #pragma unroll
  for (int j=0;j<16;j++) v[j] = xp[j]*inv + cb[j];
  float t[16];
  #pragma unroll
  for (int j=0;j<16;j++){
    float acc = bL[j];
    #pragma unroll
    for (int k=0;k<16;k++) acc += v[k]*wL[j*16+k];
    t[j] = fmaxf(acc, 0.f);
  }
  float y0 = b2L[0], y1 = b2L[1];
  #pragma unroll
  for (int k=0;k<16;k++){ y0 += t[k]*w2L[k]; y1 += t[k]*w2L[16+k]; }
  y0 = fmaxf(y0, 0.f); y1 = fmaxf(y1, 0.f);
  float m = fmaxf(y0, y1);
  float l = m + __logf(__expf(y0-m) + __expf(y1-m));
  float2 no; no.x = y0-l; no.y = y1-l;
  ((float2*)nout)[n] = no;
}

extern "C" void kernel_launch(void* const* d_in, const int* in_sizes, int n_in,
                              void* d_out, int out_size, void* d_ws, size_t ws_size,
                              hipStream_t stream)
{
  const float* x  = (const float*)d_in[0];
  const int* ei   = (const int*)d_in[1];
  const float* ea = (const float*)d_in[2];
  const float* c1Wx = (const float*)d_in[3];
  const float* c1We = (const float*)d_in[4];
  const float* c1as = (const float*)d_in[5];
  const float* c1ad = (const float*)d_in[6];
  const float* c1ae = (const float*)d_in[7];
  const float* c1b  = (const float*)d_in[8];
  const float* e1w1 = (const float*)d_in[9];
  const float* e1b1 = (const float*)d_in[10];
  const float* e1w2 = (const float*)d_in[11];
  const float* e1b2 = (const float*)d_in[12];
  const float* e1w3 = (const float*)d_in[13];
  const float* e1b3 = (const float*)d_in[14];
  const float* e1w4 = (const float*)d_in[15];
  const float* e1b4 = (const float*)d_in[16];
  const float* c2Wx = (const float*)d_in[17];
  const float* c2We = (const float*)d_in[18];
  const float* c2as = (const float*)d_in[19];
  const float* c2ad = (const float*)d_in[20];
  const float* c2ae = (const float*)d_in[21];
  const float* c2b  = (const float*)d_in[22];
  const float* nlw1 = (const float*)d_in[23];
  const float* nlb1 = (const float*)d_in[24];
  const float* nlw2 = (const float*)d_in[25];
  const float* nlb2 = (const float*)d_in[26];
  const float* elw1 = (const float*)d_in[27];
  const float* elb1 = (const float*)d_in[28];
  const float* elw2 = (const float*)d_in[29];
  const float* elb2 = (const float*)d_in[30];

  float* ws = (float*)d_ws;
  const size_t N = NN;
  int* off   = (int*)ws;                     // N+8
  int* cnt   = (int*)ws + (N + 8);           // N
  int* bsum  = (int*)ws + (2*N + 8);         // 128
  int* boff  = (int*)ws + (2*N + 136);       // 128
  u32* hpk   = (u32*)(ws + 2*N + 264);       // 8N u32 (f16x2-packed h1/h2)
  float* hs  = ws + 10*N + 264;              // N
  float* hd  = hs + N;                       // N
  float* acc = hd + N;                       // 16N
  float* s   = acc + 16*N;                   // N
  u32* uh    = (u32*)(s + N);                // 16N u32
  u32* vh    = uh + 16*N;                    // 16N u32
  float2* edata = (float2*)(vh + 16*N);      // NE float2

  float* nout = (float*)d_out;               // [100000, 2]
  float* eout = (float*)d_out + 200000;      // [3200000, 4]

  const int GE = (NE + 255)/256;
  const int GN = (NN + 255)/256;

  (void)hipMemsetAsync(cnt, 0, N*sizeof(int), stream);
  khist<<<GE, 256, 0, stream>>>(ei, cnt);
  kscanA<<<NB, 1024, 0, stream>>>(cnt, bsum);
  kscanB<<<1, 64, 0, stream>>>(bsum, boff, off + NN);
  kscanC<<<NB, 1024, 0, stream>>>(cnt, boff, off);
  k1<<<GN, 256, 0, stream>>>(x, c1Wx, c1as, c1ad, hpk, hs, hd);
  k2a<<<GE, 256, 0, stream>>>(ei, ea, c1We, c1ae, hs, hd, off, cnt, edata);
  kagg<<<(NN+15)/16, 256, 0, stream>>>(edata, off, (const u16*)hpk, acc, s, cnt);
  k4<<<GN, 256, 0, stream>>>(acc, s, c1b, c2Wx, c2as, c2ad, e1w1, hpk, hs, hd, uh, vh);
  k5<<<GE, 256, 0, stream>>>(ei, ea, uh, vh, hs, hd,
      e1w1, e1b1, e1w2, e1b2, e1w3, e1b3, e1w4, e1b4,
      c2We, c2ae, elw1, elb1, elw2, elb2,
      off, cnt, edata, eout);
  kagg<<<(NN+15)/16, 256, 0, stream>>>(edata, off, (const u16*)hpk, acc, s, cnt);
  k7<<<GN, 256, 0, stream>>>(acc, s, c2b, nlw1, nlb1, nlw2, nlb2, nout);
}

// Round 14
// 745.214 us; speedup vs baseline: 11.3334x; 1.0784x over previous
//
#include <hip/hip_runtime.h>

#define NN 100000
#define NE 3200000
#define NB 98   // ceil(NN/1024)

typedef unsigned int u32;
typedef unsigned short u16;
typedef _Float16 f16x2 __attribute__((ext_vector_type(2)));
typedef __fp16 fp16v2 __attribute__((ext_vector_type(2)));

__device__ __forceinline__ int clampi(int s){
  s = s < 0 ? 0 : s;
  return s >= NN ? NN-1 : s;
}

__device__ __forceinline__ f16x2 pk2(float x, float y){
  fp16v2 r = __builtin_amdgcn_cvt_pkrtz(x, y);
  return __builtin_bit_cast(f16x2, r);
}
__device__ __forceinline__ float dot2(f16x2 a, f16x2 b, float c){
  return __builtin_amdgcn_fdot2(a, b, c, false);
}
__device__ __forceinline__ float f16lo(u32 w){
  __fp16 h = __builtin_bit_cast(__fp16, (u16)(w & 0xffffu));
  return (float)h;
}
__device__ __forceinline__ float f16hi(u32 w){
  __fp16 h = __builtin_bit_cast(__fp16, (u16)(w >> 16));
  return (float)h;
}
__device__ __forceinline__ float f16u(u16 w){
  __fp16 h = __builtin_bit_cast(__fp16, w);
  return (float)h;
}

// dual-accumulator dot (f32, used by k4)
template<int N4>
__device__ __forceinline__ float dotl(const float* __restrict__ a, const float* w){
  float acc0 = 0.f, acc1 = 0.f;
  #pragma unroll
  for (int k = 0; k < N4; k += 2){
    float4 q0 = ((const float4*)w)[k];
    acc0 += a[4*k]*q0.x + a[4*k+1]*q0.y + a[4*k+2]*q0.z + a[4*k+3]*q0.w;
    float4 q1 = ((const float4*)w)[k+1];
    acc1 += a[4*k+4]*q1.x + a[4*k+5]*q1.y + a[4*k+6]*q1.z + a[4*k+7]*q1.w;
  }
  return acc0 + acc1;
}

// ---------------- khist: cnt[d]++ ------------------------------------------
__global__ __launch_bounds__(256,8) void khist(const int* __restrict__ ei, int* __restrict__ cnt){
  int i = blockIdx.x*256 + threadIdx.x;
  if (i >= NE) return;
  atomicAdd(&cnt[clampi(ei[NE+i])], 1);
}

// ---------------- kscanA: per-block sums of cnt -----------------------------
__global__ __launch_bounds__(1024) void kscanA(const int* __restrict__ cnt, int* __restrict__ bsum){
  __shared__ int wsum[16];
  int tid = threadIdx.x;
  int i = blockIdx.x*1024 + tid;
  int x = (i < NN) ? cnt[i] : 0;
  #pragma unroll
  for (int ofs = 1; ofs < 64; ofs <<= 1) x += __shfl_xor(x, ofs, 64);
  if ((tid & 63) == 0) wsum[tid >> 6] = x;
  __syncthreads();
  if (tid == 0){
    int t = 0;
    #pragma unroll
    for (int k = 0; k < 16; k++) t += wsum[k];
    bsum[blockIdx.x] = t;
  }
}

// ---------------- kscanB: scan the 98 block sums ----------------------------
__global__ void kscanB(const int* __restrict__ bsum, int* __restrict__ boff, int* __restrict__ offN){
  if (threadIdx.x == 0){
    int c = 0;
    for (int b = 0; b < NB; b++){ boff[b] = c; c += bsum[b]; }
    offN[0] = c;
  }
}

// ---------------- kscanC: block-local scan + offset; cnt = 0 ----------------
__global__ __launch_bounds__(1024) void kscanC(int* __restrict__ cnt, const int* __restrict__ boff,
                                               int* __restrict__ off){
  __shared__ int wsum[16];
  int tid = threadIdx.x;
  int i = blockIdx.x*1024 + tid;
  int v = (i < NN) ? cnt[i] : 0;
  int x = v;
  #pragma unroll
  for (int ofs = 1; ofs < 64; ofs <<= 1){
    int t = __shfl_up(x, ofs, 64);
    if ((tid & 63) >= ofs) x += t;
  }
  if ((tid & 63) == 63) wsum[tid >> 6] = x;
  __syncthreads();
  if (tid < 16){
    int y = wsum[tid];
    #pragma unroll
    for (int ofs = 1; ofs < 16; ofs <<= 1){
      int t = __shfl_up(y, ofs, 64);
      if (tid >= ofs) y += t;
    }
    wsum[tid] = y;
  }
  __syncthreads();
  int wb = (tid >= 64) ? wsum[(tid >> 6) - 1] : 0;
  if (i < NN){ off[i] = boff[blockIdx.x] + wb + x - v; cnt[i] = 0; }
}

// ---------------- k1: hs1 = (Wx x).a_src ; hd1 = (Wx x).a_dst ---------------
// h1 itself is never materialized: conv1 aggregation works on x (linearity).
__global__ __launch_bounds__(256,4) void k1(const float* __restrict__ x,
    const float* __restrict__ Wx, const float* __restrict__ asrc, const float* __restrict__ adst,
    float* __restrict__ hs1, float* __restrict__ hd1)
{
  __shared__ float wL[64], aS[16], aD[16];
  int tid = threadIdx.x;
  if (tid < 64) wL[tid] = Wx[tid];
  if (tid < 16){ aS[tid] = asrc[tid]; aD[tid] = adst[tid]; }
  __syncthreads();
  int n = blockIdx.x*256 + tid;
  if (n >= NN) return;
  float4 xr = ((const float4*)x)[n];
  float hs=0.f, hd=0.f;
  #pragma unroll
  for (int j=0;j<16;j++){
    float h = xr.x*wL[j*4+0] + xr.y*wL[j*4+1] + xr.z*wL[j*4+2] + xr.w*wL[j*4+3];
    hs += h*aS[j]; hd += h*aD[j];
  }
  hs1[n]=hs; hd1[n]=hd;
}

// ---------------- k2a: alpha1 -> scatter (ex, src) into CSR slot ------------
__global__ __launch_bounds__(256,8) void k2a(const int* __restrict__ ei,
    const float* __restrict__ ea, const float* __restrict__ We, const float* __restrict__ aedge,
    const float* __restrict__ hs1, const float* __restrict__ hd1,
    const int* __restrict__ off, int* __restrict__ cnt, float2* __restrict__ edata)
{
  __shared__ float w6[6];
  int tid = threadIdx.x;
  if (tid < 6){
    float acc = 0.f;
    for (int j=0;j<16;j++) acc += aedge[j] * We[j*6+tid];
    w6[tid] = acc;
  }
  __syncthreads();
  int i = blockIdx.x*256 + tid;
  if (i >= NE) return;
  int s = clampi(ei[i]);
  int d = clampi(ei[NE + i]);
  const float2* eap = (const float2*)ea + (size_t)i*3;
  float2 u0 = eap[0], u1 = eap[1], u2 = eap[2];
  float al = hs1[s] + hd1[d]
    + u0.x*w6[0] + u0.y*w6[1] + u1.x*w6[2]
    + u1.y*w6[3] + u2.x*w6[4] + u2.y*w6[5];
  al = al > 0.f ? al : 0.2f*al;
  float ex = __expf(al);
  int pos = off[d] + atomicAdd(&cnt[d], 1);
  edata[pos] = make_float2(ex, __int_as_float(s));
}

// ---------------- kaggx: conv1 agg over x (4 feat x 4 k-slots / 16 lanes) ---
__global__ __launch_bounds__(256,8) void kaggx(const float2* __restrict__ edata,
    const int* __restrict__ off, const float* __restrict__ x,
    float* __restrict__ acc4, float* __restrict__ s, int* __restrict__ cnt)
{
  int t = blockIdx.x*256 + threadIdx.x;
  int n = t >> 4;
  int j = t & 15;        // f = j&3, ks = j>>2
  if (n >= NN) return;
  int f = j & 3, ks = j >> 2;
  int beg = off[n], end = off[n+1];
  float aj = 0.f, sl = 0.f;
  for (int k = beg + ks; k < end; k += 4){
    float2 p = edata[k];
    int src = __float_as_int(p.y);
    aj += p.x * x[(size_t)src*4 + f];
    sl += p.x;
  }
  // reduce over ks (lane bits 2,3)
  aj += __shfl_xor(aj, 4, 64); aj += __shfl_xor(aj, 8, 64);
  sl += __shfl_xor(sl, 4, 64); sl += __shfl_xor(sl, 8, 64);
  if (ks == 0) acc4[(size_t)n*4 + f] = aj;
  if (j == 0){ s[n] = sl; cnt[n] = 0; }
}

// ---------------- kagg2: conv2 agg over hpk (16 feat x 4 k-slots / 64 lanes)
__global__ __launch_bounds__(256,8) void kagg2(const float2* __restrict__ edata,
    const int* __restrict__ off, const u16* __restrict__ hpk,
    float* __restrict__ acc, float* __restrict__ s, int* __restrict__ cnt)
{
  int t = blockIdx.x*256 + threadIdx.x;
  int n = t >> 6;
  int l = t & 63;        // j = l&15 feature, ks = l>>4
  if (n >= NN) return;
  int j = l & 15, ks = l >> 4;
  int beg = off[n], end = off[n+1];
  float aj = 0.f, sl = 0.f;
  for (int k = beg + ks; k < end; k += 4){
    float2 p = edata[k];
    int src = __float_as_int(p.y);
    aj += p.x * f16u(hpk[(size_t)src*16 + j]);
    sl += p.x;
  }
  // reduce over ks (lane bits 4,5)
  aj += __shfl_xor(aj, 16, 64); aj += __shfl_xor(aj, 32, 64);
  sl += __shfl_xor(sl, 16, 64); sl += __shfl_xor(sl, 32, 64);
  if (ks == 0) acc[(size_t)n*16 + j] = aj;
  if (l == 0){ s[n] = sl; cnt[n] = 0; }
}

// ---------------- k4: x1 = Wx1.(acc4/s) + b1 ; h2 ; hs2 ; hd2 ; u,v ---------
__global__ __launch_bounds__(256,2) void k4(const float* __restrict__ acc4,
    const float* __restrict__ sb, const float* __restrict__ c1b,
    const float* __restrict__ Wx1, const float* __restrict__ Wx2,
    const float* __restrict__ a2s, const float* __restrict__ a2d,
    const float* __restrict__ w1p,
    u32* __restrict__ hpk,
    float* __restrict__ hs2, float* __restrict__ hd2,
    u32* __restrict__ uh, u32* __restrict__ vh)
{
  __shared__ float wL[256], bL[16], aS[16], aD[16], w0L[64];
  __shared__ float w1sL[32*16], w1dL[32*16];
  int tid = threadIdx.x;
  wL[tid] = Wx2[tid];
  if (tid < 64) w0L[tid] = Wx1[tid];
  if (tid < 16){ bL[tid]=c1b[tid]; aS[tid]=a2s[tid]; aD[tid]=a2d[tid]; }
  for (int idx=tid; idx<512; idx+=256){
    int j=idx>>4, k=idx&15;
    w1sL[idx] = w1p[j*38+k];
    w1dL[idx] = w1p[j*38+22+k];
  }
  __syncthreads();
  int n = blockIdx.x*256 + tid;
  if (n >= NN) return;
  float inv = 1.f/(sb[n] + 1e-16f);
  float4 a4 = ((const float4*)acc4)[n];
  float m0 = a4.x*inv, m1 = a4.y*inv, m2 = a4.z*inv, m3 = a4.w*inv;
  float xv[16];
  #pragma unroll
  for (int j=0;j<16;j++)
    xv[j] = m0*w0L[j*4+0] + m1*w0L[j*4+1] + m2*w0L[j*4+2] + m3*w0L[j*4+3] + bL[j];
  float hs=0.f, hd=0.f;
  float hv[16];
  #pragma unroll
  for (int j=0;j<16;j++){
    float acc = 0.f;
    #pragma unroll
    for (int k=0;k<16;k++) acc += xv[k]*wL[j*16+k];
    hv[j] = acc; hs += acc*aS[j]; hd += acc*aD[j];
  }
  u32* hr = hpk + (size_t)n*8;
  #pragma unroll
  for (int j=0;j<8;j++) hr[j] = __builtin_bit_cast(u32, pk2(hv[2*j], hv[2*j+1]));
  hs2[n]=hs; hd2[n]=hd;
  u32* ur = uh + (size_t)n*16;
  u32* vr = vh + (size_t)n*16;
  #pragma unroll
  for (int j=0;j<16;j++){
    float u0 = dotl<4>(xv, &w1sL[(2*j)*16]);
    float u1 = dotl<4>(xv, &w1sL[(2*j+1)*16]);
    ur[j] = __builtin_bit_cast(u32, pk2(u0, u1));
    float v0 = dotl<4>(xv, &w1dL[(2*j)*16]);
    float v1 = dotl<4>(xv, &w1dL[(2*j+1)*16]);
    vr[j] = __builtin_bit_cast(u32, pk2(v0, v1));
  }
}

// ---------------- k5: edge MLP (f16 dot2) + edge head + alpha2 scatter ------
// (256,5): known-good from r13 (371us, VGPR 48, no spill). UNCHANGED.
__global__ __launch_bounds__(256,5) void k5(
    const int* __restrict__ ei, const float* __restrict__ ea,
    const u32* __restrict__ uh, const u32* __restrict__ vh,
    const float* __restrict__ hs2, const float* __restrict__ hd2,
    const float* w1p, const float* b1p, const float* w2p, const float* b2p,
    const float* w3p, const float* b3p, const float* w4p, const float* b4p,
    const float* We2, const float* a2e,
    const float* ew1p, const float* eb1p, const float* ew2p, const float* eb2p,
    const int* __restrict__ off, int* __restrict__ cnt, float2* __restrict__ edata,
    float* __restrict__ eout)
{
  __shared__ __align__(16) f16x2 w1eh[32*4];  __shared__ float b1L[32];
  __shared__ __align__(16) f16x2 w2h[64*16];  __shared__ float b2L[64];
  __shared__ __align__(16) f16x2 w3h[32*32];  __shared__ float b3L[32];
  __shared__ __align__(16) f16x2 w4h[16*16];  __shared__ float b4L[16];
  __shared__ __align__(16) f16x2 ew1h[16*8];  __shared__ float eb1L[16];
  __shared__ __align__(16) f16x2 ew2h[4*8];   __shared__ float eb2L[4];
  __shared__ __align__(16) f16x2 w16h[8];
  int tid = threadIdx.x;
  if (tid < 128){
    int j=tid>>2, kk=tid&3;
    int k0=2*kk, k1=2*kk+1;
    float v0 = (k0<6) ? w1p[j*38+16+k0] : 0.f;
    float v1 = (k1<6) ? w1p[j*38+16+k1] : 0.f;
    w1eh[tid] = pk2(v0, v1);
  }
  for (int idx=tid; idx<1024; idx+=256){
    int j=idx>>4, kk=idx&15;
    w2h[idx] = pk2(w2p[j*32+2*kk], w2p[j*32+2*kk+1]);
  }
  for (int idx=tid; idx<1024; idx+=256){
    int j=idx>>5, kk=idx&31;
    w3h[idx] = pk2(w3p[j*64+2*kk], w3p[j*64+2*kk+1]);
  }
  if (tid < 256){
    int j=tid>>4, kk=tid&15;
    w4h[tid] = pk2(w4p[j*32+2*kk], w4p[j*32+2*kk+1]);
  }
  if (tid < 128){
    int j=tid>>3, kk=tid&7;
    ew1h[tid] = pk2(ew1p[j*16+2*kk], ew1p[j*16+2*kk+1]);
  }
  if (tid < 32){
    int j=tid>>3, kk=tid&7;
    ew2h[tid] = pk2(ew2p[j*16+2*kk], ew2p[j*16+2*kk+1]);
  }
  if (tid < 8){
    float s0=0.f, s1=0.f;
    for (int j=0;j<16;j++){
      s0 += a2e[j] * We2[j*16 + 2*tid];
      s1 += a2e[j] * We2[j*16 + 2*tid + 1];
    }
    w16h[tid] = pk2(s0, s1);
  }
  if (tid < 64) b2L[tid] = b2p[tid];
  if (tid < 32){ b1L[tid] = b1p[tid]; b3L[tid] = b3p[tid]; }
  if (tid < 16){ b4L[tid] = b4p[tid]; eb1L[tid] = eb1p[tid]; }
  if (tid < 4)  eb2L[tid] = eb2p[tid];
  __syncthreads();

  int i = blockIdx.x*256 + tid;
  if (i >= NE) return;
  int s = clampi(ei[i]);
  int d = clampi(ei[NE + i]);

  // ---- layer 1: a1 = relu(u[s] + v[d] + W1e.ea + b1) ----
  f16x2 a1h[16];
  {
    const float2* eap = (const float2*)ea + (size_t)i*3;
    float2 e0=eap[0], e1=eap[1], e2=eap[2];
    f16x2 eh[4];
    eh[0]=pk2(e0.x,e0.y); eh[1]=pk2(e1.x,e1.y); eh[2]=pk2(e2.x,e2.y); eh[3]=pk2(0.f,0.f);
    const uint4* up = (const uint4*)(uh + (size_t)s*16);
    const uint4* vp = (const uint4*)(vh + (size_t)d*16);
    uint4 U[4], V[4];
    #pragma unroll
    for (int q=0;q<4;q++){ U[q]=up[q]; V[q]=vp[q]; }
    u32 uw[16], vw[16];
    #pragma unroll
    for (int q=0;q<4;q++){
      uw[4*q]=U[q].x; uw[4*q+1]=U[q].y; uw[4*q+2]=U[q].z; uw[4*q+3]=U[q].w;
      vw[4*q]=V[q].x; vw[4*q+1]=V[q].y; vw[4*q+2]=V[q].z; vw[4*q+3]=V[q].w;
    }
    #pragma unroll
    for (int j=0;j<16;j++){
      float t0 = b1L[2*j]   + f16lo(uw[j]) + f16lo(vw[j]);
      float t1 = b1L[2*j+1] + f16hi(uw[j]) + f16hi(vw[j]);
      #pragma unroll
      for (int kk=0;kk<4;kk++){
        t0 = dot2(eh[kk], w1eh[(2*j)*4+kk],   t0);
        t1 = dot2(eh[kk], w1eh[(2*j+1)*4+kk], t1);
      }
      a1h[j] = pk2(fmaxf(t0,0.f), fmaxf(t1,0.f));
    }
  }
  // ---- layer 2: 32 -> 64 ----
  f16x2 a2h[32];
  #pragma unroll
  for (int j=0;j<32;j++){
    float acc0 = b2L[2*j], acc1 = b2L[2*j+1];
    #pragma unroll
    for (int kk=0;kk<16;kk++){
      acc0 = dot2(a1h[kk], w2h[(2*j)*16+kk],   acc0);
      acc1 = dot2(a1h[kk], w2h[(2*j+1)*16+kk], acc1);
    }
    a2h[j] = pk2(fmaxf(acc0,0.f), fmaxf(acc1,0.f));
  }
  // ---- layer 3: 64 -> 32 ----
  f16x2 a3h[16];
  #pragma unroll
  for (int j=0;j<16;j++){
    float acc0 = b3L[2*j], acc1 = b3L[2*j+1];
    #pragma unroll
    for (int kk=0;kk<32;kk++){
      acc0 = dot2(a2h[kk], w3h[(2*j)*32+kk],   acc0);
      acc1 = dot2(a2h[kk], w3h[(2*j+1)*32+kk], acc1);
    }
    a3h[j] = pk2(fmaxf(acc0,0.f), fmaxf(acc1,0.f));
  }
  // ---- layer 4: 32 -> 16 (no relu) ----
  f16x2 eh4[8];
  #pragma unroll
  for (int j=0;j<8;j++){
    float acc0 = b4L[2*j], acc1 = b4L[2*j+1];
    #pragma unroll
    for (int kk=0;kk<16;kk++){
      acc0 = dot2(a3h[kk], w4h[(2*j)*16+kk],   acc0);
      acc1 = dot2(a3h[kk], w4h[(2*j+1)*16+kk], acc1);
    }
    eh4[j] = pk2(acc0, acc1);
  }
  // ---- edge head + log_softmax(4) ----
  f16x2 th[8];
  #pragma unroll
  for (int j=0;j<8;j++){
    float acc0 = eb1L[2*j], acc1 = eb1L[2*j+1];
    #pragma unroll
    for (int kk=0;kk<8;kk++){
      acc0 = dot2(eh4[kk], ew1h[(2*j)*8+kk],   acc0);
      acc1 = dot2(eh4[kk], ew1h[(2*j+1)*8+kk], acc1);
    }
    th[j] = pk2(fmaxf(acc0,0.f), fmaxf(acc1,0.f));
  }
  float y0 = eb2L[0], y1 = eb2L[1], y2 = eb2L[2], y3 = eb2L[3];
  #pragma unroll
  for (int kk=0;kk<8;kk++){
    y0 = dot2(th[kk], ew2h[0*8+kk], y0);
    y1 = dot2(th[kk], ew2h[1*8+kk], y1);
    y2 = dot2(th[kk], ew2h[2*8+kk], y2);
    y3 = dot2(th[kk], ew2h[3*8+kk], y3);
  }
  y0 = fmaxf(y0,0.f); y1 = fmaxf(y1,0.f); y2 = fmaxf(y2,0.f); y3 = fmaxf(y3,0.f);
  float m = fmaxf(fmaxf(y0,y1), fmaxf(y2,y3));
  float l = m + __logf(__expf(y0-m)+__expf(y1-m)+__expf(y2-m)+__expf(y3-m));
  float4 eo; eo.x = y0-l; eo.y = y1-l; eo.z = y2-l; eo.w = y3-l;
  ((float4*)eout)[i] = eo;

  // ---- conv2 alpha -> CSR scatter ----
  float al = hs2[s] + hd2[d];
  #pragma unroll
  for (int kk=0;kk<8;kk++) al = dot2(eh4[kk], w16h[kk], al);
  al = al > 0.f ? al : 0.2f*al;
  float ex = __expf(al);
  int pos = off[d] + atomicAdd(&cnt[d], 1);
  edata[pos] = make_float2(ex, __int_as_float(s));
}

// ---------------- k7: x2 -> node head -> log_softmax(2) --------------------
__global__ __launch_bounds__(256,4) void k7(const float* __restrict__ accb,
    const float* __restrict__ sb, const float* __restrict__ c2b,
    const float* __restrict__ w1p, const float* __restrict__ b1p,
    const float* __restrict__ w2p, const float* __restrict__ b2p,
    float* __restrict__ nout)
{
  __shared__ float wL[256], bL[16], w2L[32], b2L[2], cb[16];
  int tid = threadIdx.x;
  wL[tid] = w1p[tid];
  if (tid < 16){ bL[tid]=b1p[tid]; cb[tid]=c2b[tid]; }
  if (tid < 32) w2L[tid] = w2p[tid];
  if (tid < 2)  b2L[tid] = b2p[tid];
  __syncthreads();
  int n = blockIdx.x*256 + tid;
  if (n >= NN) return;
  float inv = 1.f/(sb[n] + 1e-16f);
  const float* xp = accb + (size_t)n*16;
  float v[16];
  #pragma unroll
  for (int j=0;j<16;j++) v[j] = xp[j]*inv + cb[j];
  float t[16];
  #pragma unroll
  for (int j=0;j<16;j++){
    float acc = bL[j];
    #pragma unroll
    for (int k=0;k<16;k++) acc += v[k]*wL[j*16+k];
    t[j] = fmaxf(acc, 0.f);
  }
  float y0 = b2L[0], y1 = b2L[1];
  #pragma unroll
  for (int k=0;k<16;k++){ y0 += t[k]*w2L[k]; y1 += t[k]*w2L[16+k]; }
  y0 = fmaxf(y0, 0.f); y1 = fmaxf(y1, 0.f);
  float m = fmaxf(y0, y1);
  float l = m + __logf(__expf(y0-m) + __expf(y1-m));
  float2 no; no.x = y0-l; no.y = y1-l;
  ((float2*)nout)[n] = no;
}

extern "C" void kernel_launch(void* const* d_in, const int* in_sizes, int n_in,
                              void* d_out, int out_size, void* d_ws, size_t ws_size,
                              hipStream_t stream)
{
  const float* x  = (const float*)d_in[0];
  const int* ei   = (const int*)d_in[1];
  const float* ea = (const float*)d_in[2];
  const float* c1Wx = (const float*)d_in[3];
  const float* c1We = (const float*)d_in[4];
  const float* c1as = (const float*)d_in[5];
  const float* c1ad = (const float*)d_in[6];
  const float* c1ae = (const float*)d_in[7];
  const float* c1b  = (const float*)d_in[8];
  const float* e1w1 = (const float*)d_in[9];
  const float* e1b1 = (const float*)d_in[10];
  const float* e1w2 = (const float*)d_in[11];
  const float* e1b2 = (const float*)d_in[12];
  const float* e1w3 = (const float*)d_in[13];
  const float* e1b3 = (const float*)d_in[14];
  const float* e1w4 = (const float*)d_in[15];
  const float* e1b4 = (const float*)d_in[16];
  const float* c2Wx = (const float*)d_in[17];
  const float* c2We = (const float*)d_in[18];
  const float* c2as = (const float*)d_in[19];
  const float* c2ad = (const float*)d_in[20];
  const float* c2ae = (const float*)d_in[21];
  const float* c2b  = (const float*)d_in[22];
  const float* nlw1 = (const float*)d_in[23];
  const float* nlb1 = (const float*)d_in[24];
  const float* nlw2 = (const float*)d_in[25];
  const float* nlb2 = (const float*)d_in[26];
  const float* elw1 = (const float*)d_in[27];
  const float* elb1 = (const float*)d_in[28];
  const float* elw2 = (const float*)d_in[29];
  const float* elb2 = (const float*)d_in[30];

  float* ws = (float*)d_ws;
  const size_t N = NN;
  int* off   = (int*)ws;                     // N+8
  int* cnt   = (int*)ws + (N + 8);           // N
  int* bsum  = (int*)ws + (2*N + 8);         // 128
  int* boff  = (int*)ws + (2*N + 136);       // 128
  u32* hpk   = (u32*)(ws + 2*N + 264);       // 8N u32 (f16x2-packed h2)
  float* hs  = ws + 10*N + 264;              // N
  float* hd  = hs + N;                       // N
  float* acc = hd + N;                       // 16N (conv2 agg)
  float* acc4= acc + 16*N;                   // 4N  (conv1 agg of x)
  float* s   = acc4 + 4*N;                   // N
  u32* uh    = (u32*)(s + N);                // 16N u32
  u32* vh    = uh + 16*N;                    // 16N u32
  float2* edata = (float2*)(vh + 16*N);      // NE float2

  float* nout = (float*)d_out;               // [100000, 2]
  float* eout = (float*)d_out + 200000;      // [3200000, 4]

  const int GE = (NE + 255)/256;
  const int GN = (NN + 255)/256;

  (void)hipMemsetAsync(cnt, 0, N*sizeof(int), stream);
  khist<<<GE, 256, 0, stream>>>(ei, cnt);
  kscanA<<<NB, 1024, 0, stream>>>(cnt, bsum);
  kscanB<<<1, 64, 0, stream>>>(bsum, boff, off + NN);
  kscanC<<<NB, 1024, 0, stream>>>(cnt, boff, off);
  k1<<<GN, 256, 0, stream>>>(x, c1Wx, c1as, c1ad, hs, hd);
  k2a<<<GE, 256, 0, stream>>>(ei, ea, c1We, c1ae, hs, hd, off, cnt, edata);
  kaggx<<<(NN*16 + 255)/256, 256, 0, stream>>>(edata, off, x, acc4, s, cnt);
  k4<<<GN, 256, 0, stream>>>(acc4, s, c1b, c1Wx, c2Wx, c2as, c2ad, e1w1, hpk, hs, hd, uh, vh);
  k5<<<GE, 256, 0, stream>>>(ei, ea, uh, vh, hs, hd,
      e1w1, e1b1, e1w2, e1b2, e1w3, e1b3, e1w4, e1b4,
      c2We, c2ae, elw1, elb1, elw2, elb2,
      off, cnt, edata, eout);
  kagg2<<<(NN*64 + 255)/256, 256, 0, stream>>>(edata, off, (const u16*)hpk, acc, s, cnt);
  k7<<<GN, 256, 0, stream>>>(acc, s, c2b, nlw1, nlb1, nlw2, nlb2, nout);
}